// Round 16
// baseline (132.093 us; speedup 1.0000x reference)
//
#include <hip/hip_runtime.h>
#include <math.h>

#define BG   16
#define NPG  400
#define NN   (BG*NPG)      // 6400 nodes
#define KNN  20
#define NH   8
#define HD   16
#define EM   128
#define NL   3
#define NEGS 0.2f
#define BNEPS 1e-5f
#define MAXDEG 128
#define NSLOT 7            // ceil(400/64) candidates per lane
#define SPAD 16            // floats per BN-stat slot (64B anti-contention padding)
#define KNB  800           // knn blocks (8 waves x 1 node each)
#define MMB  400           // mm tiles (16 rows each, 512 threads)
#define ANB  (NN/16)       // attn blocks: 16 nodes each (8 waves x 2 nodes, ILP-2)

typedef unsigned short ushortx;

__device__ __forceinline__ ushortx f2bf(float x) {   // round-to-nearest-even bf16
    unsigned b = __float_as_uint(x);
    return (ushortx)((b + 0x7FFFu + ((b >> 16) & 1u)) >> 16);
}

// ------- kNN: wave per node, RADIX-SELECT top-20, LDS-staged positions ------
__device__ __forceinline__ void knn_radix(const float* __restrict__ pos,
                                          int* __restrict__ fwd, int bid,
                                          float* __restrict__ ps,   // >= 800 floats LDS
                                          int* __restrict__ ctr) {
    int wave = threadIdx.x >> 6, lane = threadIdx.x & 63;
    int i = bid * 8 + wave;             // global node (8 consecutive, same graph)
    int g = i / NPG, li = i - g * NPG;
    const float* pg = pos + (size_t)g * NPG * 2;
    for (int idx = threadIdx.x; idx < NPG * 2; idx += 512) ps[idx] = pg[idx];
    __syncthreads();
    float xi = ps[li * 2], yi = ps[li * 2 + 1];

    unsigned kk[NSLOT], kx[NSLOT];      // key bits; key ^ selected-prefix
    #pragma unroll
    for (int s = 0; s < NSLOT; ++s) {
        int j = lane + (s << 6);
        unsigned kb = 0x7F800000u;      // +inf for invalid/self
        if (j < NPG && j != li) {
            float dx = __fsub_rn(xi, ps[j * 2]);
            float dy = __fsub_rn(yi, ps[j * 2 + 1]);
            float d2 = __fadd_rn(__fmul_rn(dx, dx), __fmul_rn(dy, dy));  // exact np rounding
            kb = __float_as_uint(d2);
        }
        kk[s] = kb; kx[s] = kb;
    }

    // MSB radix select: P = 20th-smallest key; R = #needed among ==P
    unsigned P = 0; int R = KNN;
    #pragma unroll
    for (int bit = 29; bit >= 0; --bit) {
        int c = 0;
        #pragma unroll
        for (int s = 0; s < NSLOT; ++s)
            c += __popcll(__ballot(kx[s] < (1u << bit)));   // prefix-match AND bit==0
        unsigned delta = (R > c) ? (1u << bit) : 0u;
        R -= (R > c) ? c : 0;
        P |= delta;
        #pragma unroll
        for (int s = 0; s < NSLOT; ++s) kx[s] ^= delta;
    }

    bool sel[NSLOT];
    int nsel = 0;
    #pragma unroll
    for (int s = 0; s < NSLOT; ++s) { sel[s] = kk[s] < P; nsel += sel[s] ? 1 : 0; }

    // threshold keys (kx==0 <=> kk==P): fast path when no real tie competition
    int ceq = 0;
    #pragma unroll
    for (int s = 0; s < NSLOT; ++s) ceq += __popcll(__ballot(kx[s] == 0u));
    if (ceq == R) {
        #pragma unroll
        for (int s = 0; s < NSLOT; ++s)
            if (kx[s] == 0u) { sel[s] = true; nsel++; }
        R = 0;
    }
    #pragma unroll 1
    while (R > 0) {                     // rare: ties at threshold, take smallest j
        int bj = 0x7FFFFFFF;
        #pragma unroll
        for (int s = 0; s < NSLOT; ++s)
            if (kx[s] == 0 && !sel[s]) { int j = lane + (s << 6); bj = j < bj ? j : bj; }
        int m = bj;
        #pragma unroll
        for (int off = 32; off > 0; off >>= 1) { int o = __shfl_xor(m, off); m = o < m ? o : m; }
        if (bj == m && bj != 0x7FFFFFFF) {
            #pragma unroll
            for (int s = 0; s < NSLOT; ++s)
                if ((lane + (s << 6)) == bj) { sel[s] = true; nsel++; }
        }
        R--;
    }

    // emit (order-free set)
    if (lane == 0) ctr[wave] = 0;
    int pos0 = atomicAdd(&ctr[wave], nsel);
    int w = 0;
    #pragma unroll
    for (int s = 0; s < NSLOT; ++s)
        if (sel[s]) { fwd[(size_t)i * KNN + pos0 + w] = lane + (s << 6); ++w; }
}

// ---- mm tile (16 rows, 512 thr): [proj | BN+ELU+res] + hh(bf16) + scores ---
__device__ __forceinline__ void mm_tile(
        int tile, float* __restrict__ h, const float* __restrict__ gout,
        const float* __restrict__ stat, const float* __restrict__ gamma,
        const float* __restrict__ beta, const float* __restrict__ x,
        const float* __restrict__ pw, const float* __restrict__ pb,
        const float* __restrict__ w,
        const float* __restrict__ asrc, const float* __restrict__ adst,
        ushortx* __restrict__ hhb, float* __restrict__ ssrc, float* __restrict__ sdst,
        float (*hs)[EM]) {
    int t = threadIdx.x;               // 0..511
    int row0 = tile * 16;
    for (int idx = t; idx < 16 * EM; idx += 512) {
        int r = idx >> 7, c = idx & 127;
        size_t gi = (size_t)(row0 + r) * EM + c;
        float v;
        if (gout) {
            float m  = stat[c * SPAD] * (1.f / NN);
            float vr = stat[(128 + c) * SPAD] * (1.f / NN) - m * m;
            float bnv = (gout[gi] - m) * rsqrtf(vr + BNEPS) * gamma[c] + beta[c];
            bnv = bnv > 0.f ? bnv : __expf(bnv) - 1.f;   // elu (fast exp)
            v = bnv + h[gi];                        // residual
        } else {
            int n = row0 + r;                       // input projection
            v = x[n * 3 + 0] * pw[c] + x[n * 3 + 1] * pw[EM + c]
              + x[n * 3 + 2] * pw[2 * EM + c] + pb[c];
        }
        h[gi] = v;
        hs[r][c] = v;
    }
    __syncthreads();
    int cc = t & 127, q = t >> 7;      // q in 0..3 -> rows q*4+rr
    float acc[4] = {0, 0, 0, 0};
    const float* wp = w + cc;
    for (int k = 0; k < EM; k += 4) {
        float w0 = wp[(k + 0) * EM], w1 = wp[(k + 1) * EM];
        float w2 = wp[(k + 2) * EM], w3 = wp[(k + 3) * EM];
        #pragma unroll
        for (int rr = 0; rr < 4; ++rr) {
            const float4 hv = *(const float4*)&hs[q * 4 + rr][k];
            acc[rr] = fmaf(hv.x, w0, fmaf(hv.y, w1, fmaf(hv.z, w2, fmaf(hv.w, w3, acc[rr]))));
        }
    }
    #pragma unroll
    for (int rr = 0; rr < 4; ++rr)
        hhb[(size_t)(row0 + q * 4 + rr) * EM + cc] = f2bf(acc[rr]);   // bf16 for PV
    __syncthreads();
    #pragma unroll
    for (int rr = 0; rr < 4; ++rr) hs[q * 4 + rr][cc] = acc[rr];      // fp32 for scores
    __syncthreads();
    if (t < 16 * NH) {
        int row = t >> 3, hd = t & 7;
        const float* ap = asrc + hd * HD;
        const float* dp = adst + hd * HD;
        float s1 = 0.f, s2 = 0.f;
        #pragma unroll
        for (int d = 0; d < HD; ++d) {
            float v = hs[row][hd * HD + d];
            s1 += v * ap[d]; s2 += v * dp[d];
        }
        ssrc[(size_t)(row0 + row) * NH + hd] = s1;
        sdst[(size_t)(row0 + row) * NH + hd] = s2;
    }
}

// ---- kernel 1: kNN (blocks 0..799)  ||  layer-0 mm (blocks 800..1199) ------
__global__ __launch_bounds__(512) void k1_kernel(
        const float* __restrict__ pos, int* __restrict__ fwd,
        float* __restrict__ h, const float* __restrict__ x,
        const float* __restrict__ pw, const float* __restrict__ pb,
        const float* __restrict__ w0,
        const float* __restrict__ asrc0, const float* __restrict__ adst0,
        ushortx* __restrict__ hhb, float* __restrict__ ssrc, float* __restrict__ sdst,
        float* __restrict__ statz, float* __restrict__ out) {
    __shared__ float hs[16][EM];
    __shared__ int ctr[8];
    int bid = blockIdx.x;
    if (bid < KNB) {
        knn_radix(pos, fwd, bid, (float*)hs, ctr);
    } else {
        int tile = bid - KNB;
        if (tile == 0) {
            if (threadIdx.x < 256) statz[threadIdx.x * SPAD] = 0.f;
        } else if (tile == 1) {
            for (int idx = threadIdx.x; idx < BG * EM; idx += 512)
                out[(size_t)NN * EM + idx] = 0.f;   // zero graph-mean tail
        }
        mm_tile(tile, h, nullptr, nullptr, nullptr, nullptr,
                x, pw, pb, w0, asrc0, adst0, hhb, ssrc, sdst, hs);
    }
}

// ---- mm kernel for layers 1,2 (zeroes next stat accumulator) ---------------
__global__ __launch_bounds__(512) void mm_kernel(
        float* __restrict__ h, const float* __restrict__ gout,
        const float* __restrict__ stat, const float* __restrict__ gamma,
        const float* __restrict__ beta, const float* __restrict__ w,
        const float* __restrict__ asrc, const float* __restrict__ adst,
        ushortx* __restrict__ hhb, float* __restrict__ ssrc, float* __restrict__ sdst,
        float* __restrict__ statz) {
    __shared__ float hs[16][EM];
    if (blockIdx.x == 0 && threadIdx.x < 256) statz[threadIdx.x * SPAD] = 0.f;
    mm_tile(blockIdx.x, h, gout, stat, gamma, beta,
            nullptr, nullptr, nullptr, w, asrc, adst, hhb, ssrc, sdst, hs);
}

// ---- attention: 16 nodes/block, 2 nodes/wave ILP-2; FIRST builds adjacency -
template<int FIRST>
__global__ __launch_bounds__(512) void attn_kernel(const ushortx* __restrict__ hhb,
                                                   const int* __restrict__ fwd,
                                                   const float* __restrict__ ssrc,
                                                   const float* __restrict__ sdst,
                                                   const float* __restrict__ bias,
                                                   float* __restrict__ gout,
                                                   float* __restrict__ statl,
                                                   int* __restrict__ nbrg,
                                                   int* __restrict__ cntg) {
    __shared__ float sc[16 * 1024];           // per-NODE score slab [jj*8+hd] (64 KB)
    __shared__ int   nb[16][MAXDEG];          // graph-LOCAL neighbor ids (8 KB)
    __shared__ int cnt16[16];
    __shared__ float red[256];
    int t = threadIdx.x, wv = t >> 6, lane = t & 63;
    int bid = blockIdx.x;
    int g = bid / 25;                          // 25 blocks per graph (400/16)
    int r0g = (bid - g * 25) * 16;             // graph-local row base
    int sbase = g * NPG;

    if (t < 256) red[t] = 0.f;

    if (FIRST) {
        __shared__ unsigned bm[16][16];       // 16 rows x 512-bit adjacency
        __shared__ unsigned short roff[16][13];
        if (t < 256) ((unsigned*)bm)[t] = 0u;
        __syncthreads();
        const int* fg = fwd + (size_t)sbase * KNN;
        for (int e = t; e < NPG * KNN; e += 512) {
            int src = e / KNN;                 // graph-local
            int dst = fg[e];                   // graph-local
            int rs = src - r0g, rd = dst - r0g;
            if ((unsigned)rs < 16u) atomicOr(&bm[rs][dst >> 5], 1u << (dst & 31));
            if ((unsigned)rd < 16u) atomicOr(&bm[rd][src >> 5], 1u << (src & 31));
        }
        if (t < 16) atomicOr(&bm[t][(r0g + t) >> 5], 1u << ((r0g + t) & 31));  // self
        __syncthreads();
        if (t < 16) {                          // prefix popcounts per row
            int off = 0;
            #pragma unroll
            for (int w = 0; w < 13; ++w) { roff[t][w] = (unsigned short)off; off += __popc(bm[t][w]); }
            cnt16[t] = off < MAXDEG ? off : MAXDEG;
            cntg[bid * 16 + t] = cnt16[t];
        }
        __syncthreads();
        if (t < 16 * 13) {                     // (row,word) emit tasks
            int row = t / 13, w = t - row * 13;
            unsigned m = bm[row][w];
            int c = roff[row][w];
            int jb = w * 32;
            while (m) {
                int b = __ffs(m) - 1;
                m &= m - 1;
                if (c < MAXDEG) nb[row][c++] = jb + b;
            }
        }
        __syncthreads();
        // persist for layers 1,2 (coalesced; wave wv owns rows 2wv, 2wv+1)
        #pragma unroll
        for (int r2 = 0; r2 < 2; ++r2) {
            int row = wv * 2 + r2;
            int c = cnt16[row];
            int* dst = nbrg + ((size_t)bid * 16 + row) * MAXDEG;
            for (int j = lane; j < c; j += 64) dst[j] = nb[row][j];
        }
    } else {
        if (t < 16) cnt16[t] = cntg[bid * 16 + t];
        __syncthreads();
        #pragma unroll
        for (int r2 = 0; r2 < 2; ++r2) {
            int row = wv * 2 + r2;
            int c = cnt16[row];
            const int* src = nbrg + ((size_t)bid * 16 + row) * MAXDEG;
            for (int j = lane; j < c; j += 64) nb[row][j] = src[j];
        }
        __syncthreads();
    }

    int nloA = wv * 2, nloB = nloA + 1;
    int iA = bid * 16 + nloA, iB = iA + 1;
    int cA = cnt16[nloA], cB = cnt16[nloB];
    int cpm = ((cA > cB ? cA : cB) + 3) & ~3;  // shared padded bound (x4)
    for (int j = cA + lane; j < cpm; j += 64) nb[nloA][j] = r0g + nloA;  // self pads
    for (int j = cB + lane; j < cpm; j += 64) nb[nloB][j] = r0g + nloB;

    float* scA = sc + nloA * 1024;
    float* scB = sc + nloB * 1024;
    int hd = lane & 7, sub = lane >> 3, h0 = lane >> 3;

    // score fill, both nodes per iteration (independent gathers)
    float sdA = sdst[iA * NH + hd];
    float sdB = sdst[iB * NH + hd];
    for (int idx = lane; idx < cpm * NH; idx += 64) {      // idx&7 == lane&7
        int jj = idx >> 3;
        float vA = 0.f, vB = 0.f;
        if (jj < cA) {
            vA = sdA + ssrc[(size_t)(sbase + nb[nloA][jj]) * NH + hd];
            vA = vA >= 0.f ? vA : NEGS * vA;
        }
        if (jj < cB) {
            vB = sdB + ssrc[(size_t)(sbase + nb[nloB][jj]) * NH + hd];
            vB = vB >= 0.f ? vB : NEGS * vB;
        }
        scA[idx] = vA;                        // pads = 0 (PV no-op)
        scB[idx] = vB;
    }
    asm volatile("s_waitcnt lgkmcnt(0)" ::: "memory");

    // softmax, two independent chains interleaved
    float mxA = -INFINITY, mxB = -INFINITY;
    for (int jj = sub; jj < cA; jj += 8) mxA = fmaxf(mxA, scA[jj * 8 + hd]);
    for (int jj = sub; jj < cB; jj += 8) mxB = fmaxf(mxB, scB[jj * 8 + hd]);
    #pragma unroll
    for (int off = 8; off < 64; off <<= 1) {
        mxA = fmaxf(mxA, __shfl_xor(mxA, off));
        mxB = fmaxf(mxB, __shfl_xor(mxB, off));
    }
    float sA = 0.f, sB = 0.f;
    for (int jj = sub; jj < cA; jj += 8) {
        float e = __expf(scA[jj * 8 + hd] - mxA);
        scA[jj * 8 + hd] = e;
        sA += e;
    }
    for (int jj = sub; jj < cB; jj += 8) {
        float e = __expf(scB[jj * 8 + hd] - mxB);
        scB[jj * 8 + hd] = e;
        sB += e;
    }
    #pragma unroll
    for (int off = 8; off < 64; off <<= 1) {
        sA += __shfl_xor(sA, off);
        sB += __shfl_xor(sB, off);
    }
    float invA = 1.f / sA, invB = 1.f / sB;   // lane k (k<8) holds head k
    asm volatile("s_waitcnt lgkmcnt(0)" ::: "memory");

    // PV fused over both nodes: 4 independent gathers per 2-neighbor step
    float invhA = __shfl(invA, h0);
    float invhB = __shfl(invB, h0);
    const unsigned* hp32 = (const unsigned*)hhb;
    float a0A = 0.f, a1A = 0.f, a0B = 0.f, a1B = 0.f;
    for (int jj = 0; jj < cpm; jj += 2) {
        float wA0 = scA[(jj + 0) * 8 + h0];
        float wA1 = scA[(jj + 1) * 8 + h0];
        float wB0 = scB[(jj + 0) * 8 + h0];
        float wB1 = scB[(jj + 1) * 8 + h0];
        unsigned uA0 = hp32[(size_t)(sbase + nb[nloA][jj + 0]) * 64 + lane];
        unsigned uA1 = hp32[(size_t)(sbase + nb[nloA][jj + 1]) * 64 + lane];
        unsigned uB0 = hp32[(size_t)(sbase + nb[nloB][jj + 0]) * 64 + lane];
        unsigned uB1 = hp32[(size_t)(sbase + nb[nloB][jj + 1]) * 64 + lane];
        a0A += wA0 * __uint_as_float(uA0 << 16) + wA1 * __uint_as_float(uA1 << 16);
        a1A += wA0 * __uint_as_float(uA0 & 0xFFFF0000u) + wA1 * __uint_as_float(uA1 & 0xFFFF0000u);
        a0B += wB0 * __uint_as_float(uB0 << 16) + wB1 * __uint_as_float(uB1 << 16);
        a1B += wB0 * __uint_as_float(uB0 & 0xFFFF0000u) + wB1 * __uint_as_float(uB1 & 0xFFFF0000u);
    }
    float2 bv = *(const float2*)(bias + 2 * lane);
    float v0A = a0A * invhA + bv.x, v1A = a1A * invhA + bv.y;
    float v0B = a0B * invhB + bv.x, v1B = a1B * invhB + bv.y;
    float2 ovA; ovA.x = v0A; ovA.y = v1A;
    float2 ovB; ovB.x = v0B; ovB.y = v1B;
    *(float2*)(gout + (size_t)iA * EM + 2 * lane) = ovA;
    *(float2*)(gout + (size_t)iB * EM + 2 * lane) = ovB;

    // BN stat partials: channels 2*lane, 2*lane+1; one pass for both nodes
    atomicAdd(&red[2 * lane], v0A + v0B);
    atomicAdd(&red[2 * lane + 1], v1A + v1B);
    atomicAdd(&red[128 + 2 * lane], v0A * v0A + v0B * v0B);
    atomicAdd(&red[128 + 2 * lane + 1], v1A * v1A + v1B * v1B);
    __syncthreads();
    if (t < 256)
        atomicAdd(&statl[t * SPAD], red[t]);
}

// ---- final: BN+ELU+residual (layer 2) -> node out + graph-mean atomics -----
__global__ __launch_bounds__(256) void finish_kernel(const float* __restrict__ gout,
                                                     const float* __restrict__ stat,
                                                     const float* __restrict__ gamma,
                                                     const float* __restrict__ beta,
                                                     const float* __restrict__ h,
                                                     float* __restrict__ out) {
    int b = blockIdx.x;          // 16 graphs x 8 chunks of 50 rows
    int g = b >> 3, ch = b & 7;
    int t = threadIdx.x, c = t & 127, half = t >> 7;
    float m  = stat[c * SPAD] * (1.f / NN);
    float vr = stat[(128 + c) * SPAD] * (1.f / NN) - m * m;
    float rs = rsqrtf(vr + BNEPS);
    float ga = gamma[c], be = beta[c];
    int r0 = g * NPG + ch * 50;
    float s = 0.f;
    for (int k = half; k < 50; k += 2) {
        size_t gi = (size_t)(r0 + k) * EM + c;
        float v = (gout[gi] - m) * rs * ga + be;
        v = v > 0.f ? v : __expf(v) - 1.f;
        v += h[gi];
        out[gi] = v;
        s += v;
    }
    __shared__ float l1[256];
    l1[t] = s;
    __syncthreads();
    if (half == 0)
        atomicAdd(&out[(size_t)NN * EM + g * EM + c], (l1[c] + l1[c + 128]) * (1.f / NPG));
}

extern "C" void kernel_launch(void* const* d_in, const int* in_sizes, int n_in,
                              void* d_out, int out_size, void* d_ws, size_t ws_size,
                              hipStream_t stream) {
    const float* x      = (const float*)d_in[0];
    const float* pos    = (const float*)d_in[1];
    // d_in[2] = batch (int32), unused: graphs are contiguous blocks of 400
    const float* proj_w = (const float*)d_in[3];
    const float* proj_b = (const float*)d_in[4];
    const float* lin_w  = (const float*)d_in[5];
    const float* asrc   = (const float*)d_in[6];
    const float* adst   = (const float*)d_in[7];
    const float* gbias  = (const float*)d_in[8];
    const float* gamma  = (const float*)d_in[9];
    const float* beta   = (const float*)d_in[10];
    float* out = (float*)d_out;

    char* p = (char*)d_ws;
    auto take = [&](size_t bytes) { char* q = p; p += (bytes + 63) & ~(size_t)63; return q; };
    int*     fwd  = (int*)take((size_t)NN * KNN * 4);
    int*     nbrg = (int*)take((size_t)NN * MAXDEG * 4);
    int*     cntg = (int*)take((size_t)NN * 4);
    float*   h    = (float*)take((size_t)NN * EM * 4);
    ushortx* hhb  = (ushortx*)take((size_t)NN * EM * 2);
    float*   gout = (float*)take((size_t)NN * EM * 4);
    float*   ssrc = (float*)take((size_t)NN * NH * 4);
    float*   sdst = (float*)take((size_t)NN * NH * 4);
    float*   statA = (float*)take((size_t)256 * SPAD * 4);
    float*   statB = (float*)take((size_t)256 * SPAD * 4);
    float*   statv[2] = {statA, statB};

    // 1: kNN (radix, LDS pos) || layer-0 mm (+zero statv[0], out tail)
    k1_kernel<<<KNB + MMB, 512, 0, stream>>>(pos, fwd, h, x, proj_w, proj_b,
                                             lin_w, asrc, adst, hhb, ssrc, sdst,
                                             statv[0], out);
    // 2: attn layer 0 (builds + persists adjacency) -> statv[0]
    attn_kernel<1><<<ANB, 512, 0, stream>>>(hhb, fwd, ssrc, sdst, gbias, gout,
                                            statv[0], nbrg, cntg);
    // 3: mm layer 1 (reads statv[0], zeroes statv[1])
    mm_kernel<<<MMB, 512, 0, stream>>>(h, gout, statv[0], gamma, beta,
                                       lin_w + (size_t)EM * EM, asrc + EM, adst + EM,
                                       hhb, ssrc, sdst, statv[1]);
    // 4: attn layer 1 (loads adjacency) -> statv[1]
    attn_kernel<0><<<ANB, 512, 0, stream>>>(hhb, fwd, ssrc, sdst, gbias + EM, gout,
                                            statv[1], nbrg, cntg);
    // 5: mm layer 2 (reads statv[1], zeroes statv[0])
    mm_kernel<<<MMB, 512, 0, stream>>>(h, gout, statv[1], gamma + EM, beta + EM,
                                       lin_w + (size_t)2 * EM * EM, asrc + 2 * EM, adst + 2 * EM,
                                       hhb, ssrc, sdst, statv[0]);
    // 6: attn layer 2 (loads adjacency) -> statv[0]
    attn_kernel<0><<<ANB, 512, 0, stream>>>(hhb, fwd, ssrc, sdst, gbias + 2 * EM, gout,
                                            statv[0], nbrg, cntg);
    // 7: finish
    finish_kernel<<<BG * 8, 256, 0, stream>>>(gout, statv[0],
                                              gamma + 2 * EM, beta + 2 * EM, h, out);
}

// Round 17
// 128.051 us; speedup vs baseline: 1.0316x; 1.0316x over previous
//
#include <hip/hip_runtime.h>
#include <math.h>

#define BG   16
#define NPG  400
#define NN   (BG*NPG)      // 6400 nodes
#define KNN  20
#define NH   8
#define HD   16
#define EM   128
#define NL   3
#define NEGS 0.2f
#define BNEPS 1e-5f
#define MAXDEG 128
#define NSLOT 7            // ceil(400/64) candidates per lane
#define SPAD 16            // floats per BN-stat slot (64B anti-contention padding)
#define KNB  400           // knn blocks (8 waves x 2 nodes = 16 nodes each)
#define MMB  400           // mm tiles (16 rows each, 512 threads)
#define ANB  (NN/16)       // attn blocks: 16 nodes each (8 waves x 2 nodes serial)

typedef unsigned short ushortx;

__device__ __forceinline__ ushortx f2bf(float x) {   // round-to-nearest-even bf16
    unsigned b = __float_as_uint(x);
    return (ushortx)((b + 0x7FFFu + ((b >> 16) & 1u)) >> 16);
}

// --- kNN: wave per 2 nodes, RADIX-SELECT top-20, LDS-staged positions -------
__device__ __forceinline__ void knn_radix(const float* __restrict__ pos,
                                          int* __restrict__ fwd, int bid,
                                          float* __restrict__ ps,   // >= 800 floats LDS
                                          int* __restrict__ ctr) {
    int wave = threadIdx.x >> 6, lane = threadIdx.x & 63;
    int g = bid / 25;                   // 25 blocks per graph (16 nodes each)
    const float* pg = pos + (size_t)g * NPG * 2;
    for (int idx = threadIdx.x; idx < NPG * 2; idx += 512) ps[idx] = pg[idx];
    __syncthreads();

    #pragma unroll 1
    for (int r2 = 0; r2 < 2; ++r2) {
        int i = bid * 16 + wave * 2 + r2;   // global node
        int li = i - g * NPG;               // graph-local index
        float xi = ps[li * 2], yi = ps[li * 2 + 1];

        unsigned kk[NSLOT], kx[NSLOT];      // key bits; key ^ selected-prefix
        #pragma unroll
        for (int s = 0; s < NSLOT; ++s) {
            int j = lane + (s << 6);
            unsigned kb = 0x7F800000u;      // +inf for invalid/self
            if (j < NPG && j != li) {
                float dx = __fsub_rn(xi, ps[j * 2]);
                float dy = __fsub_rn(yi, ps[j * 2 + 1]);
                float d2 = __fadd_rn(__fmul_rn(dx, dx), __fmul_rn(dy, dy));  // exact np rounding
                kb = __float_as_uint(d2);
            }
            kk[s] = kb; kx[s] = kb;
        }

        // MSB radix select: P = 20th-smallest key; R = #needed among ==P
        unsigned P = 0; int R = KNN;
        #pragma unroll
        for (int bit = 29; bit >= 0; --bit) {
            int c = 0;
            #pragma unroll
            for (int s = 0; s < NSLOT; ++s)
                c += __popcll(__ballot(kx[s] < (1u << bit)));   // prefix-match AND bit==0
            unsigned delta = (R > c) ? (1u << bit) : 0u;
            R -= (R > c) ? c : 0;
            P |= delta;
            #pragma unroll
            for (int s = 0; s < NSLOT; ++s) kx[s] ^= delta;
        }

        bool sel[NSLOT];
        int nsel = 0;
        #pragma unroll
        for (int s = 0; s < NSLOT; ++s) { sel[s] = kk[s] < P; nsel += sel[s] ? 1 : 0; }

        // threshold keys (kx==0 <=> kk==P): fast path when no tie competition
        int ceq = 0;
        #pragma unroll
        for (int s = 0; s < NSLOT; ++s) ceq += __popcll(__ballot(kx[s] == 0u));
        if (ceq == R) {
            #pragma unroll
            for (int s = 0; s < NSLOT; ++s)
                if (kx[s] == 0u) { sel[s] = true; nsel++; }
            R = 0;
        }
        #pragma unroll 1
        while (R > 0) {                 // rare: ties at threshold, take smallest j
            int bj = 0x7FFFFFFF;
            #pragma unroll
            for (int s = 0; s < NSLOT; ++s)
                if (kx[s] == 0 && !sel[s]) { int j = lane + (s << 6); bj = j < bj ? j : bj; }
            int m = bj;
            #pragma unroll
            for (int off = 32; off > 0; off >>= 1) { int o = __shfl_xor(m, off); m = o < m ? o : m; }
            if (bj == m && bj != 0x7FFFFFFF) {
                #pragma unroll
                for (int s = 0; s < NSLOT; ++s)
                    if ((lane + (s << 6)) == bj) { sel[s] = true; nsel++; }
            }
            R--;
        }

        // emit (order-free set); per-wave LDS counter (wave-lockstep safe)
        if (lane == 0) ctr[wave] = 0;
        int pos0 = atomicAdd(&ctr[wave], nsel);
        int w = 0;
        #pragma unroll
        for (int s = 0; s < NSLOT; ++s)
            if (sel[s]) { fwd[(size_t)i * KNN + pos0 + w] = lane + (s << 6); ++w; }
    }
}

// ---- mm tile (16 rows, 512 thr): [proj | BN+ELU+res] + hh(bf16) + scores ---
__device__ __forceinline__ void mm_tile(
        int tile, float* __restrict__ h, const float* __restrict__ gout,
        const float* __restrict__ stat, const float* __restrict__ gamma,
        const float* __restrict__ beta, const float* __restrict__ x,
        const float* __restrict__ pw, const float* __restrict__ pb,
        const float* __restrict__ w,
        const float* __restrict__ asrc, const float* __restrict__ adst,
        ushortx* __restrict__ hhb, float* __restrict__ ssrc, float* __restrict__ sdst,
        float (*hs)[EM]) {
    int t = threadIdx.x;               // 0..511
    int row0 = tile * 16;
    for (int idx = t; idx < 16 * EM; idx += 512) {
        int r = idx >> 7, c = idx & 127;
        size_t gi = (size_t)(row0 + r) * EM + c;
        float v;
        if (gout) {
            float m  = stat[c * SPAD] * (1.f / NN);
            float vr = stat[(128 + c) * SPAD] * (1.f / NN) - m * m;
            float bnv = (gout[gi] - m) * rsqrtf(vr + BNEPS) * gamma[c] + beta[c];
            bnv = bnv > 0.f ? bnv : __expf(bnv) - 1.f;   // elu (fast exp)
            v = bnv + h[gi];                        // residual
        } else {
            int n = row0 + r;                       // input projection
            v = x[n * 3 + 0] * pw[c] + x[n * 3 + 1] * pw[EM + c]
              + x[n * 3 + 2] * pw[2 * EM + c] + pb[c];
        }
        h[gi] = v;
        hs[r][c] = v;
    }
    __syncthreads();
    int cc = t & 127, q = t >> 7;      // q in 0..3 -> rows q*4+rr
    float acc[4] = {0, 0, 0, 0};
    const float* wp = w + cc;
    for (int k = 0; k < EM; k += 4) {
        float w0 = wp[(k + 0) * EM], w1 = wp[(k + 1) * EM];
        float w2 = wp[(k + 2) * EM], w3 = wp[(k + 3) * EM];
        #pragma unroll
        for (int rr = 0; rr < 4; ++rr) {
            const float4 hv = *(const float4*)&hs[q * 4 + rr][k];
            acc[rr] = fmaf(hv.x, w0, fmaf(hv.y, w1, fmaf(hv.z, w2, fmaf(hv.w, w3, acc[rr]))));
        }
    }
    #pragma unroll
    for (int rr = 0; rr < 4; ++rr)
        hhb[(size_t)(row0 + q * 4 + rr) * EM + cc] = f2bf(acc[rr]);   // bf16 for PV
    __syncthreads();
    #pragma unroll
    for (int rr = 0; rr < 4; ++rr) hs[q * 4 + rr][cc] = acc[rr];      // fp32 for scores
    __syncthreads();
    if (t < 16 * NH) {
        int row = t >> 3, hd = t & 7;
        const float* ap = asrc + hd * HD;
        const float* dp = adst + hd * HD;
        float s1 = 0.f, s2 = 0.f;
        #pragma unroll
        for (int d = 0; d < HD; ++d) {
            float v = hs[row][hd * HD + d];
            s1 += v * ap[d]; s2 += v * dp[d];
        }
        ssrc[(size_t)(row0 + row) * NH + hd] = s1;
        sdst[(size_t)(row0 + row) * NH + hd] = s2;
    }
}

// ---- kernel 1: kNN (blocks 0..399)  ||  layer-0 mm (blocks 400..799) -------
__global__ __launch_bounds__(512) void k1_kernel(
        const float* __restrict__ pos, int* __restrict__ fwd,
        float* __restrict__ h, const float* __restrict__ x,
        const float* __restrict__ pw, const float* __restrict__ pb,
        const float* __restrict__ w0,
        const float* __restrict__ asrc0, const float* __restrict__ adst0,
        ushortx* __restrict__ hhb, float* __restrict__ ssrc, float* __restrict__ sdst,
        float* __restrict__ statz, float* __restrict__ out) {
    __shared__ float hs[16][EM];
    __shared__ int ctr[8];
    int bid = blockIdx.x;
    if (bid < KNB) {
        knn_radix(pos, fwd, bid, (float*)hs, ctr);
    } else {
        int tile = bid - KNB;
        if (tile == 0) {
            if (threadIdx.x < 256) statz[threadIdx.x * SPAD] = 0.f;
        } else if (tile == 1) {
            for (int idx = threadIdx.x; idx < BG * EM; idx += 512)
                out[(size_t)NN * EM + idx] = 0.f;   // zero graph-mean tail
        }
        mm_tile(tile, h, nullptr, nullptr, nullptr, nullptr,
                x, pw, pb, w0, asrc0, adst0, hhb, ssrc, sdst, hs);
    }
}

// ---- mm kernel for layers 1,2 (zeroes next stat accumulator) ---------------
__global__ __launch_bounds__(512) void mm_kernel(
        float* __restrict__ h, const float* __restrict__ gout,
        const float* __restrict__ stat, const float* __restrict__ gamma,
        const float* __restrict__ beta, const float* __restrict__ w,
        const float* __restrict__ asrc, const float* __restrict__ adst,
        ushortx* __restrict__ hhb, float* __restrict__ ssrc, float* __restrict__ sdst,
        float* __restrict__ statz) {
    __shared__ float hs[16][EM];
    if (blockIdx.x == 0 && threadIdx.x < 256) statz[threadIdx.x * SPAD] = 0.f;
    mm_tile(blockIdx.x, h, gout, stat, gamma, beta,
            nullptr, nullptr, nullptr, w, asrc, adst, hhb, ssrc, sdst, hs);
}

// ---- attention: 16 nodes/block, 2 nodes/wave serial; FIRST builds adjacency
template<int FIRST>
__global__ __launch_bounds__(512) void attn_kernel(const ushortx* __restrict__ hhb,
                                                   const int* __restrict__ fwd,
                                                   const float* __restrict__ ssrc,
                                                   const float* __restrict__ sdst,
                                                   const float* __restrict__ bias,
                                                   float* __restrict__ gout,
                                                   float* __restrict__ statl,
                                                   int* __restrict__ nbrg,
                                                   int* __restrict__ cntg) {
    __shared__ float sc[8 * 1024];            // per-wave score slab [jj*8+hd]
    __shared__ int   nb[16][MAXDEG];          // graph-LOCAL neighbor ids (8 KB)
    __shared__ int cnt16[16];
    __shared__ float red[256];
    int t = threadIdx.x, wv = t >> 6, lane = t & 63;
    int bid = blockIdx.x;
    int g = bid / 25;                          // 25 blocks per graph (400/16)
    int r0g = (bid - g * 25) * 16;             // graph-local row base
    int sbase = g * NPG;

    if (t < 256) red[t] = 0.f;

    if (FIRST) {
        __shared__ unsigned bm[16][16];       // 16 rows x 512-bit adjacency
        __shared__ unsigned short roff[16][13];
        if (t < 256) ((unsigned*)bm)[t] = 0u;
        __syncthreads();
        const int* fg = fwd + (size_t)sbase * KNN;
        for (int e = t; e < NPG * KNN; e += 512) {
            int src = e / KNN;                 // graph-local
            int dst = fg[e];                   // graph-local
            int rs = src - r0g, rd = dst - r0g;
            if ((unsigned)rs < 16u) atomicOr(&bm[rs][dst >> 5], 1u << (dst & 31));
            if ((unsigned)rd < 16u) atomicOr(&bm[rd][src >> 5], 1u << (src & 31));
        }
        if (t < 16) atomicOr(&bm[t][(r0g + t) >> 5], 1u << ((r0g + t) & 31));  // self
        __syncthreads();
        if (t < 16) {                          // prefix popcounts per row
            int off = 0;
            #pragma unroll
            for (int w = 0; w < 13; ++w) { roff[t][w] = (unsigned short)off; off += __popc(bm[t][w]); }
            cnt16[t] = off < MAXDEG ? off : MAXDEG;
            cntg[bid * 16 + t] = cnt16[t];
        }
        __syncthreads();
        if (t < 16 * 13) {                     // (row,word) emit tasks
            int row = t / 13, w = t - row * 13;
            unsigned m = bm[row][w];
            int c = roff[row][w];
            int jb = w * 32;
            while (m) {
                int b = __ffs(m) - 1;
                m &= m - 1;
                if (c < MAXDEG) nb[row][c++] = jb + b;
            }
        }
        __syncthreads();
        // persist for layers 1,2 (coalesced; wave wv owns rows 2wv, 2wv+1)
        #pragma unroll
        for (int r2 = 0; r2 < 2; ++r2) {
            int row = wv * 2 + r2;
            int c = cnt16[row];
            int* dst = nbrg + ((size_t)bid * 16 + row) * MAXDEG;
            for (int j = lane; j < c; j += 64) dst[j] = nb[row][j];
        }
    } else {
        if (t < 16) cnt16[t] = cntg[bid * 16 + t];
        __syncthreads();
        #pragma unroll
        for (int r2 = 0; r2 < 2; ++r2) {
            int row = wv * 2 + r2;
            int c = cnt16[row];
            const int* src = nbrg + ((size_t)bid * 16 + row) * MAXDEG;
            for (int j = lane; j < c; j += 64) nb[row][j] = src[j];
        }
        __syncthreads();
    }

    float* scw = sc + wv * 1024;
    int hd = lane & 7, sub = lane >> 3, h0 = lane >> 3;
    float s1a = 0.f, s2a = 0.f, s1b = 0.f, s2b = 0.f;

    #pragma unroll 1
    for (int r2 = 0; r2 < 2; ++r2) {
        int nlo = wv * 2 + r2;                 // block-local node
        int i = bid * 16 + nlo;                // global node
        int c = cnt16[nlo];
        int cp = (c + 3) & ~3;                 // pad to x4 for PV unroll
        if (lane < cp - c) nb[nlo][c + lane] = r0g + nlo;   // valid (self) pad ids

        float sd = sdst[i * NH + hd];
        for (int idx = lane; idx < cp * NH; idx += 64) {    // idx&7 == lane&7
            int jj = idx >> 3;
            float v = 0.f;
            if (jj < c) {
                v = sd + ssrc[(size_t)(sbase + nb[nlo][jj]) * NH + hd];
                v = v >= 0.f ? v : NEGS * v;   // leaky_relu
            }
            scw[idx] = v;                      // pads = 0 (PV no-op)
        }
        asm volatile("s_waitcnt lgkmcnt(0)" ::: "memory");
        float mx = -INFINITY;
        for (int jj = sub; jj < c; jj += 8) mx = fmaxf(mx, scw[jj * 8 + hd]);
        #pragma unroll
        for (int off = 8; off < 64; off <<= 1) mx = fmaxf(mx, __shfl_xor(mx, off));
        float s = 0.f;
        for (int jj = sub; jj < c; jj += 8) {
            float e = __expf(scw[jj * 8 + hd] - mx);
            scw[jj * 8 + hd] = e;
            s += e;
        }
        #pragma unroll
        for (int off = 8; off < 64; off <<= 1) s += __shfl_xor(s, off);
        float inv = 1.f / s;                   // lane k (k<8) holds inv for head k
        asm volatile("s_waitcnt lgkmcnt(0)" ::: "memory");

        // PV: lane owns channels (2*lane, 2*lane+1) = one bf16x2 dword per nbr
        float invh = __shfl(inv, h0);
        const unsigned* hp32 = (const unsigned*)hhb;
        float acc0 = 0.f, acc1 = 0.f;
        for (int jj = 0; jj < cp; jj += 4) {
            float a0 = scw[(jj + 0) * 8 + h0];
            float a1 = scw[(jj + 1) * 8 + h0];
            float a2 = scw[(jj + 2) * 8 + h0];
            float a3 = scw[(jj + 3) * 8 + h0];
            unsigned u0 = hp32[(size_t)(sbase + nb[nlo][jj + 0]) * 64 + lane];
            unsigned u1 = hp32[(size_t)(sbase + nb[nlo][jj + 1]) * 64 + lane];
            unsigned u2 = hp32[(size_t)(sbase + nb[nlo][jj + 2]) * 64 + lane];
            unsigned u3 = hp32[(size_t)(sbase + nb[nlo][jj + 3]) * 64 + lane];
            acc0 += a0 * __uint_as_float(u0 << 16) + a1 * __uint_as_float(u1 << 16)
                  + a2 * __uint_as_float(u2 << 16) + a3 * __uint_as_float(u3 << 16);
            acc1 += a0 * __uint_as_float(u0 & 0xFFFF0000u) + a1 * __uint_as_float(u1 & 0xFFFF0000u)
                  + a2 * __uint_as_float(u2 & 0xFFFF0000u) + a3 * __uint_as_float(u3 & 0xFFFF0000u);
        }
        float2 bv = *(const float2*)(bias + 2 * lane);
        float v0 = acc0 * invh + bv.x;
        float v1 = acc1 * invh + bv.y;
        float2 ov; ov.x = v0; ov.y = v1;
        *(float2*)(gout + (size_t)i * EM + 2 * lane) = ov;
        if (r2 == 0) { s1a += v0; s2a += v0 * v0; s1b += v1; s2b += v1 * v1; }
        else         { s1a += v0; s2a += v0 * v0; s1b += v1; s2b += v1 * v1; }
    }

    // BN stat partials: channels 2*lane (a), 2*lane+1 (b); one pass for 2 nodes
    atomicAdd(&red[2 * lane], s1a);
    atomicAdd(&red[2 * lane + 1], s1b);
    atomicAdd(&red[128 + 2 * lane], s2a);
    atomicAdd(&red[128 + 2 * lane + 1], s2b);
    __syncthreads();
    if (t < 256)
        atomicAdd(&statl[t * SPAD], red[t]);
}

// ---- final: BN+ELU+residual (layer 2) -> node out + graph-mean atomics -----
__global__ __launch_bounds__(256) void finish_kernel(const float* __restrict__ gout,
                                                     const float* __restrict__ stat,
                                                     const float* __restrict__ gamma,
                                                     const float* __restrict__ beta,
                                                     const float* __restrict__ h,
                                                     float* __restrict__ out) {
    int b = blockIdx.x;          // 16 graphs x 8 chunks of 50 rows
    int g = b >> 3, ch = b & 7;
    int t = threadIdx.x, c = t & 127, half = t >> 7;
    float m  = stat[c * SPAD] * (1.f / NN);
    float vr = stat[(128 + c) * SPAD] * (1.f / NN) - m * m;
    float rs = rsqrtf(vr + BNEPS);
    float ga = gamma[c], be = beta[c];
    int r0 = g * NPG + ch * 50;
    float s = 0.f;
    for (int k = half; k < 50; k += 2) {
        size_t gi = (size_t)(r0 + k) * EM + c;
        float v = (gout[gi] - m) * rs * ga + be;
        v = v > 0.f ? v : __expf(v) - 1.f;
        v += h[gi];
        out[gi] = v;
        s += v;
    }
    __shared__ float l1[256];
    l1[t] = s;
    __syncthreads();
    if (half == 0)
        atomicAdd(&out[(size_t)NN * EM + g * EM + c], (l1[c] + l1[c + 128]) * (1.f / NPG));
}

extern "C" void kernel_launch(void* const* d_in, const int* in_sizes, int n_in,
                              void* d_out, int out_size, void* d_ws, size_t ws_size,
                              hipStream_t stream) {
    const float* x      = (const float*)d_in[0];
    const float* pos    = (const float*)d_in[1];
    // d_in[2] = batch (int32), unused: graphs are contiguous blocks of 400
    const float* proj_w = (const float*)d_in[3];
    const float* proj_b = (const float*)d_in[4];
    const float* lin_w  = (const float*)d_in[5];
    const float* asrc   = (const float*)d_in[6];
    const float* adst   = (const float*)d_in[7];
    const float* gbias  = (const float*)d_in[8];
    const float* gamma  = (const float*)d_in[9];
    const float* beta   = (const float*)d_in[10];
    float* out = (float*)d_out;

    char* p = (char*)d_ws;
    auto take = [&](size_t bytes) { char* q = p; p += (bytes + 63) & ~(size_t)63; return q; };
    int*     fwd  = (int*)take((size_t)NN * KNN * 4);
    int*     nbrg = (int*)take((size_t)NN * MAXDEG * 4);
    int*     cntg = (int*)take((size_t)NN * 4);
    float*   h    = (float*)take((size_t)NN * EM * 4);
    ushortx* hhb  = (ushortx*)take((size_t)NN * EM * 2);
    float*   gout = (float*)take((size_t)NN * EM * 4);
    float*   ssrc = (float*)take((size_t)NN * NH * 4);
    float*   sdst = (float*)take((size_t)NN * NH * 4);
    float*   statA = (float*)take((size_t)256 * SPAD * 4);
    float*   statB = (float*)take((size_t)256 * SPAD * 4);
    float*   statv[2] = {statA, statB};

    // 1: kNN (radix, 2 nodes/wave, LDS pos) || layer-0 mm (+zero stat, tail)
    k1_kernel<<<KNB + MMB, 512, 0, stream>>>(pos, fwd, h, x, proj_w, proj_b,
                                             lin_w, asrc, adst, hhb, ssrc, sdst,
                                             statv[0], out);
    // 2: attn layer 0 (builds + persists adjacency) -> statv[0]
    attn_kernel<1><<<ANB, 512, 0, stream>>>(hhb, fwd, ssrc, sdst, gbias, gout,
                                            statv[0], nbrg, cntg);
    // 3: mm layer 1 (reads statv[0], zeroes statv[1])
    mm_kernel<<<MMB, 512, 0, stream>>>(h, gout, statv[0], gamma, beta,
                                       lin_w + (size_t)EM * EM, asrc + EM, adst + EM,
                                       hhb, ssrc, sdst, statv[1]);
    // 4: attn layer 1 (loads adjacency) -> statv[1]
    attn_kernel<0><<<ANB, 512, 0, stream>>>(hhb, fwd, ssrc, sdst, gbias + EM, gout,
                                            statv[1], nbrg, cntg);
    // 5: mm layer 2 (reads statv[1], zeroes statv[0])
    mm_kernel<<<MMB, 512, 0, stream>>>(h, gout, statv[1], gamma + EM, beta + EM,
                                       lin_w + (size_t)2 * EM * EM, asrc + 2 * EM, adst + 2 * EM,
                                       hhb, ssrc, sdst, statv[0]);
    // 6: attn layer 2 (loads adjacency) -> statv[0]
    attn_kernel<0><<<ANB, 512, 0, stream>>>(hhb, fwd, ssrc, sdst, gbias + 2 * EM, gout,
                                            statv[0], nbrg, cntg);
    // 7: finish
    finish_kernel<<<BG * 8, 256, 0, stream>>>(gout, statv[0],
                                              gamma + 2 * EM, beta + 2 * EM, h, out);
}

// Round 18
// 119.223 us; speedup vs baseline: 1.1080x; 1.0740x over previous
//
#include <hip/hip_runtime.h>
#include <math.h>

#define BG   16
#define NPG  400
#define NN   (BG*NPG)      // 6400 nodes
#define KNN  20
#define NH   8
#define HD   16
#define EM   128
#define NL   3
#define NEGS 0.2f
#define BNEPS 1e-5f
#define MAXDEG 128
#define NSLOT 7            // ceil(400/64) candidates per lane
#define SPAD 16            // floats per BN-stat slot (64B anti-contention padding)
#define KNB  400           // knn blocks (8 waves x 2 nodes = 16 nodes each)
#define MMB  400           // mm tiles (16 rows each, 512 threads)
#define ANB  (NN/16)       // attn blocks: 16 nodes each (8 waves x 2 nodes serial)

typedef unsigned short ushortx;

__device__ __forceinline__ ushortx f2bf(float x) {   // round-to-nearest-even bf16
    unsigned b = __float_as_uint(x);
    return (ushortx)((b + 0x7FFFu + ((b >> 16) & 1u)) >> 16);
}

// --- kNN: wave per 2 nodes, RADIX-SELECT top-20, LDS-staged positions -------
__device__ __forceinline__ void knn_radix(const float* __restrict__ pos,
                                          int* __restrict__ fwd, int bid,
                                          float* __restrict__ ps,   // >= 800 floats LDS
                                          int* __restrict__ ctr) {
    int wave = threadIdx.x >> 6, lane = threadIdx.x & 63;
    int g = bid / 25;                   // 25 blocks per graph (16 nodes each)
    const float* pg = pos + (size_t)g * NPG * 2;
    for (int idx = threadIdx.x; idx < NPG * 2; idx += 512) ps[idx] = pg[idx];
    __syncthreads();

    #pragma unroll 1
    for (int r2 = 0; r2 < 2; ++r2) {
        int i = bid * 16 + wave * 2 + r2;   // global node
        int li = i - g * NPG;               // graph-local index
        float xi = ps[li * 2], yi = ps[li * 2 + 1];

        unsigned kk[NSLOT], kx[NSLOT];      // key bits; key ^ selected-prefix
        #pragma unroll
        for (int s = 0; s < NSLOT; ++s) {
            int j = lane + (s << 6);
            unsigned kb = 0x7F800000u;      // +inf for invalid/self
            if (j < NPG && j != li) {
                float dx = __fsub_rn(xi, ps[j * 2]);
                float dy = __fsub_rn(yi, ps[j * 2 + 1]);
                float d2 = __fadd_rn(__fmul_rn(dx, dx), __fmul_rn(dy, dy));  // exact np rounding
                kb = __float_as_uint(d2);
            }
            kk[s] = kb; kx[s] = kb;
        }

        // MSB radix select: P = 20th-smallest key; R = #needed among ==P
        unsigned P = 0; int R = KNN;
        #pragma unroll
        for (int bit = 29; bit >= 0; --bit) {
            int c = 0;
            #pragma unroll
            for (int s = 0; s < NSLOT; ++s)
                c += __popcll(__ballot(kx[s] < (1u << bit)));   // prefix-match AND bit==0
            unsigned delta = (R > c) ? (1u << bit) : 0u;
            R -= (R > c) ? c : 0;
            P |= delta;
            #pragma unroll
            for (int s = 0; s < NSLOT; ++s) kx[s] ^= delta;
        }

        bool sel[NSLOT];
        int nsel = 0;
        #pragma unroll
        for (int s = 0; s < NSLOT; ++s) { sel[s] = kk[s] < P; nsel += sel[s] ? 1 : 0; }

        // threshold keys (kx==0 <=> kk==P): fast path when no tie competition
        int ceq = 0;
        #pragma unroll
        for (int s = 0; s < NSLOT; ++s) ceq += __popcll(__ballot(kx[s] == 0u));
        if (ceq == R) {
            #pragma unroll
            for (int s = 0; s < NSLOT; ++s)
                if (kx[s] == 0u) { sel[s] = true; nsel++; }
            R = 0;
        }
        #pragma unroll 1
        while (R > 0) {                 // rare: ties at threshold, take smallest j
            int bj = 0x7FFFFFFF;
            #pragma unroll
            for (int s = 0; s < NSLOT; ++s)
                if (kx[s] == 0 && !sel[s]) { int j = lane + (s << 6); bj = j < bj ? j : bj; }
            int m = bj;
            #pragma unroll
            for (int off = 32; off > 0; off >>= 1) { int o = __shfl_xor(m, off); m = o < m ? o : m; }
            if (bj == m && bj != 0x7FFFFFFF) {
                #pragma unroll
                for (int s = 0; s < NSLOT; ++s)
                    if ((lane + (s << 6)) == bj) { sel[s] = true; nsel++; }
            }
            R--;
        }

        // emit (order-free set); per-wave LDS counter (wave-lockstep safe)
        if (lane == 0) ctr[wave] = 0;
        int pos0 = atomicAdd(&ctr[wave], nsel);
        int w = 0;
        #pragma unroll
        for (int s = 0; s < NSLOT; ++s)
            if (sel[s]) { fwd[(size_t)i * KNN + pos0 + w] = lane + (s << 6); ++w; }
    }
}

// ---- mm tile (16 rows, 512 thr): [proj | BN+ELU+res] + hh(bf16) + scores ---
__device__ __forceinline__ void mm_tile(
        int tile, float* __restrict__ h, const float* __restrict__ gout,
        const float* __restrict__ stat, const float* __restrict__ gamma,
        const float* __restrict__ beta, const float* __restrict__ x,
        const float* __restrict__ pw, const float* __restrict__ pb,
        const float* __restrict__ w,
        const float* __restrict__ asrc, const float* __restrict__ adst,
        ushortx* __restrict__ hhb, float* __restrict__ ssrc, float* __restrict__ sdst,
        float (*hs)[EM]) {
    int t = threadIdx.x;               // 0..511
    int row0 = tile * 16;
    for (int idx = t; idx < 16 * EM; idx += 512) {
        int r = idx >> 7, c = idx & 127;
        size_t gi = (size_t)(row0 + r) * EM + c;
        float v;
        if (gout) {
            float m  = stat[c * SPAD] * (1.f / NN);
            float vr = stat[(128 + c) * SPAD] * (1.f / NN) - m * m;
            float bnv = (gout[gi] - m) * rsqrtf(vr + BNEPS) * gamma[c] + beta[c];
            bnv = bnv > 0.f ? bnv : __expf(bnv) - 1.f;   // elu (fast exp)
            v = bnv + h[gi];                        // residual
        } else {
            int n = row0 + r;                       // input projection
            v = x[n * 3 + 0] * pw[c] + x[n * 3 + 1] * pw[EM + c]
              + x[n * 3 + 2] * pw[2 * EM + c] + pb[c];
        }
        h[gi] = v;
        hs[r][c] = v;
    }
    __syncthreads();
    int cc = t & 127, q = t >> 7;      // q in 0..3 -> rows q*4+rr
    float acc[4] = {0, 0, 0, 0};
    const float* wp = w + cc;
    for (int k = 0; k < EM; k += 4) {
        float w0 = wp[(k + 0) * EM], w1 = wp[(k + 1) * EM];
        float w2 = wp[(k + 2) * EM], w3 = wp[(k + 3) * EM];
        #pragma unroll
        for (int rr = 0; rr < 4; ++rr) {
            const float4 hv = *(const float4*)&hs[q * 4 + rr][k];
            acc[rr] = fmaf(hv.x, w0, fmaf(hv.y, w1, fmaf(hv.z, w2, fmaf(hv.w, w3, acc[rr]))));
        }
    }
    #pragma unroll
    for (int rr = 0; rr < 4; ++rr)
        hhb[(size_t)(row0 + q * 4 + rr) * EM + cc] = f2bf(acc[rr]);   // bf16 for PV
    __syncthreads();
    #pragma unroll
    for (int rr = 0; rr < 4; ++rr) hs[q * 4 + rr][cc] = acc[rr];      // fp32 for scores
    __syncthreads();
    if (t < 16 * NH) {
        int row = t >> 3, hd = t & 7;
        const float* ap = asrc + hd * HD;
        const float* dp = adst + hd * HD;
        float s1 = 0.f, s2 = 0.f;
        #pragma unroll
        for (int d = 0; d < HD; ++d) {
            float v = hs[row][hd * HD + d];
            s1 += v * ap[d]; s2 += v * dp[d];
        }
        ssrc[(size_t)(row0 + row) * NH + hd] = s1;
        sdst[(size_t)(row0 + row) * NH + hd] = s2;
    }
}

// ---- kernel 1: kNN (blocks 0..399)  ||  layer-0 mm (blocks 400..799) -------
__global__ __launch_bounds__(512) void k1_kernel(
        const float* __restrict__ pos, int* __restrict__ fwd,
        float* __restrict__ h, const float* __restrict__ x,
        const float* __restrict__ pw, const float* __restrict__ pb,
        const float* __restrict__ w0,
        const float* __restrict__ asrc0, const float* __restrict__ adst0,
        ushortx* __restrict__ hhb, float* __restrict__ ssrc, float* __restrict__ sdst,
        float* __restrict__ statz, float* __restrict__ out) {
    __shared__ float hs[16][EM];
    __shared__ int ctr[8];
    int bid = blockIdx.x;
    if (bid < KNB) {
        knn_radix(pos, fwd, bid, (float*)hs, ctr);
    } else {
        int tile = bid - KNB;
        if (tile == 0) {
            if (threadIdx.x < 256) statz[threadIdx.x * SPAD] = 0.f;
        } else if (tile == 1) {
            for (int idx = threadIdx.x; idx < BG * EM; idx += 512)
                out[(size_t)NN * EM + idx] = 0.f;   // zero graph-mean tail
        }
        mm_tile(tile, h, nullptr, nullptr, nullptr, nullptr,
                x, pw, pb, w0, asrc0, adst0, hhb, ssrc, sdst, hs);
    }
}

// ---- mm kernel for layers 1,2 (zeroes next stat accumulator) ---------------
__global__ __launch_bounds__(512) void mm_kernel(
        float* __restrict__ h, const float* __restrict__ gout,
        const float* __restrict__ stat, const float* __restrict__ gamma,
        const float* __restrict__ beta, const float* __restrict__ w,
        const float* __restrict__ asrc, const float* __restrict__ adst,
        ushortx* __restrict__ hhb, float* __restrict__ ssrc, float* __restrict__ sdst,
        float* __restrict__ statz) {
    __shared__ float hs[16][EM];
    if (blockIdx.x == 0 && threadIdx.x < 256) statz[threadIdx.x * SPAD] = 0.f;
    mm_tile(blockIdx.x, h, gout, stat, gamma, beta,
            nullptr, nullptr, nullptr, w, asrc, adst, hhb, ssrc, sdst, hs);
}

// ---- attention: 16 nodes/block, 2 nodes/wave serial; FIRST builds adjacency
template<int FIRST>
__global__ __launch_bounds__(512) void attn_kernel(const ushortx* __restrict__ hhb,
                                                   const int* __restrict__ fwd,
                                                   const float* __restrict__ ssrc,
                                                   const float* __restrict__ sdst,
                                                   const float* __restrict__ bias,
                                                   float* __restrict__ gout,
                                                   float* __restrict__ statl,
                                                   int* __restrict__ nbrg,
                                                   int* __restrict__ cntg) {
    __shared__ float sc[8 * 1024];            // per-wave score slab [jj*8+hd]
    __shared__ int   nb[16][MAXDEG];          // graph-LOCAL neighbor ids (8 KB)
    __shared__ int cnt16[16];
    __shared__ float red[256];
    int t = threadIdx.x, wv = t >> 6, lane = t & 63;
    int bid = blockIdx.x;
    int g = bid / 25;                          // 25 blocks per graph (400/16)
    int r0g = (bid - g * 25) * 16;             // graph-local row base
    int sbase = g * NPG;

    if (t < 256) red[t] = 0.f;
    int cA, cB;

    if (FIRST) {
        __shared__ unsigned bm[16][16];       // 16 rows x 512-bit adjacency
        __shared__ unsigned short roff[16][13];
        if (t < 256) ((unsigned*)bm)[t] = 0u;
        __syncthreads();
        const int* fg = fwd + (size_t)sbase * KNN;
        for (int e = t; e < NPG * KNN; e += 512) {
            int src = e / KNN;                 // graph-local
            int dst = fg[e];                   // graph-local
            int rs = src - r0g, rd = dst - r0g;
            if ((unsigned)rs < 16u) atomicOr(&bm[rs][dst >> 5], 1u << (dst & 31));
            if ((unsigned)rd < 16u) atomicOr(&bm[rd][src >> 5], 1u << (src & 31));
        }
        if (t < 16) atomicOr(&bm[t][(r0g + t) >> 5], 1u << ((r0g + t) & 31));  // self
        __syncthreads();
        if (t < 16) {                          // prefix popcounts per row
            int off = 0;
            #pragma unroll
            for (int w = 0; w < 13; ++w) { roff[t][w] = (unsigned short)off; off += __popc(bm[t][w]); }
            cnt16[t] = off < MAXDEG ? off : MAXDEG;
            cntg[bid * 16 + t] = cnt16[t];
        }
        __syncthreads();
        if (t < 16 * 13) {                     // (row,word) emit tasks
            int row = t / 13, w = t - row * 13;
            unsigned m = bm[row][w];
            int c = roff[row][w];
            int jb = w * 32;
            while (m) {
                int b = __ffs(m) - 1;
                m &= m - 1;
                if (c < MAXDEG) nb[row][c++] = jb + b;
            }
        }
        __syncthreads();
        // persist for layers 1,2 (coalesced; wave wv owns rows 2wv, 2wv+1)
        #pragma unroll
        for (int r2 = 0; r2 < 2; ++r2) {
            int row = wv * 2 + r2;
            int c = cnt16[row];
            int* dst = nbrg + ((size_t)bid * 16 + row) * MAXDEG;
            for (int j = lane; j < c; j += 64) dst[j] = nb[row][j];
        }
        cA = cnt16[wv * 2];
        cB = cnt16[wv * 2 + 1];
    } else {
        // per-wave: each wave only touches its own 2 rows -> no block-wide sync
        cA = cntg[bid * 16 + wv * 2];          // broadcast scalar loads
        cB = cntg[bid * 16 + wv * 2 + 1];
        const int* srcA = nbrg + ((size_t)bid * 16 + wv * 2) * MAXDEG;
        const int* srcB = srcA + MAXDEG;
        for (int j = lane; j < cA; j += 64) nb[wv * 2][j] = srcA[j];
        for (int j = lane; j < cB; j += 64) nb[wv * 2 + 1][j] = srcB[j];
        __syncthreads();                       // orders red zeroing before stat adds
    }

    float* scw = sc + wv * 1024;
    int hd = lane & 7, sub = lane >> 3, h0 = lane >> 3;
    float s1a = 0.f, s2a = 0.f, s1b = 0.f, s2b = 0.f;
    int iA = bid * 16 + wv * 2;
    float sdA = sdst[iA * NH + hd];            // hoisted: independent early loads
    float sdB = sdst[(iA + 1) * NH + hd];

    #pragma unroll 1
    for (int r2 = 0; r2 < 2; ++r2) {
        int nlo = wv * 2 + r2;                 // block-local node
        int i = iA + r2;                       // global node
        int c = r2 ? cB : cA;
        float sd = r2 ? sdB : sdA;
        int cp = (c + 3) & ~3;                 // pad to x4 for PV unroll
        if (lane < cp - c) nb[nlo][c + lane] = r0g + nlo;   // valid (self) pad ids

        for (int idx = lane; idx < cp * NH; idx += 64) {    // idx&7 == lane&7
            int jj = idx >> 3;
            float v = 0.f;
            if (jj < c) {
                v = sd + ssrc[(size_t)(sbase + nb[nlo][jj]) * NH + hd];
                v = v >= 0.f ? v : NEGS * v;   // leaky_relu
            }
            scw[idx] = v;                      // pads = 0 (PV no-op)
        }
        asm volatile("s_waitcnt lgkmcnt(0)" ::: "memory");
        float mx = -INFINITY;
        for (int jj = sub; jj < c; jj += 8) mx = fmaxf(mx, scw[jj * 8 + hd]);
        #pragma unroll
        for (int off = 8; off < 64; off <<= 1) mx = fmaxf(mx, __shfl_xor(mx, off));
        float s = 0.f;
        for (int jj = sub; jj < c; jj += 8) {
            float e = __expf(scw[jj * 8 + hd] - mx);
            scw[jj * 8 + hd] = e;
            s += e;
        }
        #pragma unroll
        for (int off = 8; off < 64; off <<= 1) s += __shfl_xor(s, off);
        float inv = 1.f / s;                   // lane k (k<8) holds inv for head k
        asm volatile("s_waitcnt lgkmcnt(0)" ::: "memory");

        // PV: lane owns channels (2*lane, 2*lane+1) = one bf16x2 dword per nbr
        float invh = __shfl(inv, h0);
        const unsigned* hp32 = (const unsigned*)hhb;
        float acc0 = 0.f, acc1 = 0.f;
        for (int jj = 0; jj < cp; jj += 4) {
            float a0 = scw[(jj + 0) * 8 + h0];
            float a1 = scw[(jj + 1) * 8 + h0];
            float a2 = scw[(jj + 2) * 8 + h0];
            float a3 = scw[(jj + 3) * 8 + h0];
            unsigned u0 = hp32[(size_t)(sbase + nb[nlo][jj + 0]) * 64 + lane];
            unsigned u1 = hp32[(size_t)(sbase + nb[nlo][jj + 1]) * 64 + lane];
            unsigned u2 = hp32[(size_t)(sbase + nb[nlo][jj + 2]) * 64 + lane];
            unsigned u3 = hp32[(size_t)(sbase + nb[nlo][jj + 3]) * 64 + lane];
            acc0 += a0 * __uint_as_float(u0 << 16) + a1 * __uint_as_float(u1 << 16)
                  + a2 * __uint_as_float(u2 << 16) + a3 * __uint_as_float(u3 << 16);
            acc1 += a0 * __uint_as_float(u0 & 0xFFFF0000u) + a1 * __uint_as_float(u1 & 0xFFFF0000u)
                  + a2 * __uint_as_float(u2 & 0xFFFF0000u) + a3 * __uint_as_float(u3 & 0xFFFF0000u);
        }
        float2 bv = *(const float2*)(bias + 2 * lane);
        float v0 = acc0 * invh + bv.x;
        float v1 = acc1 * invh + bv.y;
        float2 ov; ov.x = v0; ov.y = v1;
        *(float2*)(gout + (size_t)i * EM + 2 * lane) = ov;
        s1a += v0; s2a += v0 * v0;
        s1b += v1; s2b += v1 * v1;
    }

    // BN stat partials: channels 2*lane (a), 2*lane+1 (b); one pass for 2 nodes
    atomicAdd(&red[2 * lane], s1a);
    atomicAdd(&red[2 * lane + 1], s1b);
    atomicAdd(&red[128 + 2 * lane], s2a);
    atomicAdd(&red[128 + 2 * lane + 1], s2b);
    __syncthreads();
    if (t < 256)
        atomicAdd(&statl[t * SPAD], red[t]);
}

// ---- final: BN+ELU+residual (layer 2) -> node out + graph-mean atomics -----
__global__ __launch_bounds__(512) void finish_kernel(const float* __restrict__ gout,
                                                     const float* __restrict__ stat,
                                                     const float* __restrict__ gamma,
                                                     const float* __restrict__ beta,
                                                     const float* __restrict__ h,
                                                     float* __restrict__ out) {
    int bid = blockIdx.x;        // 400 blocks x 16 rows (25 blocks per graph)
    int g = bid / 25;
    int row0 = bid * 16;
    int t = threadIdx.x, c = t & 127;
    float m  = stat[c * SPAD] * (1.f / NN);
    float vr = stat[(128 + c) * SPAD] * (1.f / NN) - m * m;
    float rs = rsqrtf(vr + BNEPS);
    float ga = gamma[c], be = beta[c];
    float s = 0.f;
    #pragma unroll
    for (int k = 0; k < 4; ++k) {
        int idx = k * 512 + t;               // c stays t&127; row = k*4 + (t>>7)
        int r = idx >> 7;
        size_t gi = (size_t)(row0 + r) * EM + c;
        float v = (gout[gi] - m) * rs * ga + be;
        v = v > 0.f ? v : __expf(v) - 1.f;
        v += h[gi];
        out[gi] = v;
        s += v;
    }
    __shared__ float l1[512];
    l1[t] = s;
    __syncthreads();
    if (t < 128)
        atomicAdd(&out[(size_t)NN * EM + g * EM + t],
                  (l1[t] + l1[t + 128] + l1[t + 256] + l1[t + 384]) * (1.f / NPG));
}

extern "C" void kernel_launch(void* const* d_in, const int* in_sizes, int n_in,
                              void* d_out, int out_size, void* d_ws, size_t ws_size,
                              hipStream_t stream) {
    const float* x      = (const float*)d_in[0];
    const float* pos    = (const float*)d_in[1];
    // d_in[2] = batch (int32), unused: graphs are contiguous blocks of 400
    const float* proj_w = (const float*)d_in[3];
    const float* proj_b = (const float*)d_in[4];
    const float* lin_w  = (const float*)d_in[5];
    const float* asrc   = (const float*)d_in[6];
    const float* adst   = (const float*)d_in[7];
    const float* gbias  = (const float*)d_in[8];
    const float* gamma  = (const float*)d_in[9];
    const float* beta   = (const float*)d_in[10];
    float* out = (float*)d_out;

    char* p = (char*)d_ws;
    auto take = [&](size_t bytes) { char* q = p; p += (bytes + 63) & ~(size_t)63; return q; };
    int*     fwd  = (int*)take((size_t)NN * KNN * 4);
    int*     nbrg = (int*)take((size_t)NN * MAXDEG * 4);
    int*     cntg = (int*)take((size_t)NN * 4);
    float*   h    = (float*)take((size_t)NN * EM * 4);
    ushortx* hhb  = (ushortx*)take((size_t)NN * EM * 2);
    float*   gout = (float*)take((size_t)NN * EM * 4);
    float*   ssrc = (float*)take((size_t)NN * NH * 4);
    float*   sdst = (float*)take((size_t)NN * NH * 4);
    float*   statA = (float*)take((size_t)256 * SPAD * 4);
    float*   statB = (float*)take((size_t)256 * SPAD * 4);
    float*   statv[2] = {statA, statB};

    // 1: kNN (radix, 2 nodes/wave, LDS pos) || layer-0 mm (+zero stat, tail)
    k1_kernel<<<KNB + MMB, 512, 0, stream>>>(pos, fwd, h, x, proj_w, proj_b,
                                             lin_w, asrc, adst, hhb, ssrc, sdst,
                                             statv[0], out);
    // 2: attn layer 0 (builds + persists adjacency) -> statv[0]
    attn_kernel<1><<<ANB, 512, 0, stream>>>(hhb, fwd, ssrc, sdst, gbias, gout,
                                            statv[0], nbrg, cntg);
    // 3: mm layer 1 (reads statv[0], zeroes statv[1])
    mm_kernel<<<MMB, 512, 0, stream>>>(h, gout, statv[0], gamma, beta,
                                       lin_w + (size_t)EM * EM, asrc + EM, adst + EM,
                                       hhb, ssrc, sdst, statv[1]);
    // 4: attn layer 1 (loads adjacency per-wave) -> statv[1]
    attn_kernel<0><<<ANB, 512, 0, stream>>>(hhb, fwd, ssrc, sdst, gbias + EM, gout,
                                            statv[1], nbrg, cntg);
    // 5: mm layer 2 (reads statv[1], zeroes statv[0])
    mm_kernel<<<MMB, 512, 0, stream>>>(h, gout, statv[1], gamma + EM, beta + EM,
                                       lin_w + (size_t)2 * EM * EM, asrc + 2 * EM, adst + 2 * EM,
                                       hhb, ssrc, sdst, statv[0]);
    // 6: attn layer 2 (loads adjacency per-wave) -> statv[0]
    attn_kernel<0><<<ANB, 512, 0, stream>>>(hhb, fwd, ssrc, sdst, gbias + 2 * EM, gout,
                                            statv[0], nbrg, cntg);
    // 7: finish (400 blocks, matches mm tiling)
    finish_kernel<<<MMB, 512, 0, stream>>>(gout, statv[0],
                                           gamma + 2 * EM, beta + 2 * EM, h, out);
}

// Round 19
// 117.729 us; speedup vs baseline: 1.1220x; 1.0127x over previous
//
#include <hip/hip_runtime.h>
#include <math.h>

#define BG   16
#define NPG  400
#define NN   (BG*NPG)      // 6400 nodes
#define KNN  20
#define NH   8
#define HD   16
#define EM   128
#define NL   3
#define NEGS 0.2f
#define BNEPS 1e-5f
#define MAXDEG 128
#define NSLOT 7            // ceil(400/64) candidates per lane
#define SPAD 16            // floats per BN-stat slot (64B anti-contention padding)
#define KNB  400           // knn blocks (8 waves x 2 nodes = 16 nodes each)
#define MMB  400           // mm tiles (16 rows each, 512 threads)
#define ANB  (NN/16)       // attn blocks: 16 nodes each (8 waves x 2 nodes serial)

typedef unsigned short ushortx;

__device__ __forceinline__ ushortx f2bf(float x) {   // round-to-nearest-even bf16
    unsigned b = __float_as_uint(x);
    return (ushortx)((b + 0x7FFFu + ((b >> 16) & 1u)) >> 16);
}

// --- kNN: wave per 2 nodes, RADIX-SELECT top-20, LDS-staged positions -------
__device__ __forceinline__ void knn_radix(const float* __restrict__ pos,
                                          int* __restrict__ fwd, int bid,
                                          float* __restrict__ ps,   // >= 800 floats LDS
                                          int* __restrict__ ctr) {
    int wave = threadIdx.x >> 6, lane = threadIdx.x & 63;
    int g = bid / 25;                   // 25 blocks per graph (16 nodes each)
    const float* pg = pos + (size_t)g * NPG * 2;
    for (int idx = threadIdx.x; idx < NPG * 2; idx += 512) ps[idx] = pg[idx];
    __syncthreads();

    #pragma unroll 1
    for (int r2 = 0; r2 < 2; ++r2) {
        int i = bid * 16 + wave * 2 + r2;   // global node
        int li = i - g * NPG;               // graph-local index
        float xi = ps[li * 2], yi = ps[li * 2 + 1];

        unsigned kk[NSLOT], kx[NSLOT];      // key bits; key ^ selected-prefix
        #pragma unroll
        for (int s = 0; s < NSLOT; ++s) {
            int j = lane + (s << 6);
            unsigned kb = 0x7F800000u;      // +inf for invalid/self
            if (j < NPG && j != li) {
                float dx = __fsub_rn(xi, ps[j * 2]);
                float dy = __fsub_rn(yi, ps[j * 2 + 1]);
                float d2 = __fadd_rn(__fmul_rn(dx, dx), __fmul_rn(dy, dy));  // exact np rounding
                kb = __float_as_uint(d2);
            }
            kk[s] = kb; kx[s] = kb;
        }

        // MSB radix select: P = 20th-smallest key; R = #needed among ==P
        unsigned P = 0; int R = KNN;
        #pragma unroll
        for (int bit = 29; bit >= 0; --bit) {
            int c = 0;
            #pragma unroll
            for (int s = 0; s < NSLOT; ++s)
                c += __popcll(__ballot(kx[s] < (1u << bit)));   // prefix-match AND bit==0
            unsigned delta = (R > c) ? (1u << bit) : 0u;
            R -= (R > c) ? c : 0;
            P |= delta;
            #pragma unroll
            for (int s = 0; s < NSLOT; ++s) kx[s] ^= delta;
        }

        bool sel[NSLOT];
        int nsel = 0;
        #pragma unroll
        for (int s = 0; s < NSLOT; ++s) { sel[s] = kk[s] < P; nsel += sel[s] ? 1 : 0; }

        // threshold keys (kx==0 <=> kk==P): fast path when no tie competition
        int ceq = 0;
        #pragma unroll
        for (int s = 0; s < NSLOT; ++s) ceq += __popcll(__ballot(kx[s] == 0u));
        if (ceq == R) {
            #pragma unroll
            for (int s = 0; s < NSLOT; ++s)
                if (kx[s] == 0u) { sel[s] = true; nsel++; }
            R = 0;
        }
        #pragma unroll 1
        while (R > 0) {                 // rare: ties at threshold, take smallest j
            int bj = 0x7FFFFFFF;
            #pragma unroll
            for (int s = 0; s < NSLOT; ++s)
                if (kx[s] == 0 && !sel[s]) { int j = lane + (s << 6); bj = j < bj ? j : bj; }
            int m = bj;
            #pragma unroll
            for (int off = 32; off > 0; off >>= 1) { int o = __shfl_xor(m, off); m = o < m ? o : m; }
            if (bj == m && bj != 0x7FFFFFFF) {
                #pragma unroll
                for (int s = 0; s < NSLOT; ++s)
                    if ((lane + (s << 6)) == bj) { sel[s] = true; nsel++; }
            }
            R--;
        }

        // emit (order-free set); per-wave LDS counter (wave-lockstep safe)
        if (lane == 0) ctr[wave] = 0;
        int pos0 = atomicAdd(&ctr[wave], nsel);
        int w = 0;
        #pragma unroll
        for (int s = 0; s < NSLOT; ++s)
            if (sel[s]) { fwd[(size_t)i * KNN + pos0 + w] = lane + (s << 6); ++w; }
    }
}

// ---- mm tile (16 rows, 512 thr): [proj | BN+ELU+res] + hh(bf16) + scores ---
__device__ __forceinline__ void mm_tile(
        int tile, float* __restrict__ h, const float* __restrict__ gout,
        const float* __restrict__ stat, const float* __restrict__ gamma,
        const float* __restrict__ beta, const float* __restrict__ x,
        const float* __restrict__ pw, const float* __restrict__ pb,
        const float* __restrict__ w,
        const float* __restrict__ asrc, const float* __restrict__ adst,
        ushortx* __restrict__ hhb, float* __restrict__ ssrc, float* __restrict__ sdst,
        float (*hs)[EM]) {
    int t = threadIdx.x;               // 0..511
    int row0 = tile * 16;
    for (int idx = t; idx < 16 * EM; idx += 512) {
        int r = idx >> 7, c = idx & 127;
        size_t gi = (size_t)(row0 + r) * EM + c;
        float v;
        if (gout) {
            float m  = stat[c * SPAD] * (1.f / NN);
            float vr = stat[(128 + c) * SPAD] * (1.f / NN) - m * m;
            float bnv = (gout[gi] - m) * rsqrtf(vr + BNEPS) * gamma[c] + beta[c];
            bnv = bnv > 0.f ? bnv : __expf(bnv) - 1.f;   // elu (fast exp)
            v = bnv + h[gi];                        // residual
        } else {
            int n = row0 + r;                       // input projection
            v = x[n * 3 + 0] * pw[c] + x[n * 3 + 1] * pw[EM + c]
              + x[n * 3 + 2] * pw[2 * EM + c] + pb[c];
        }
        h[gi] = v;
        hs[r][c] = v;
    }
    __syncthreads();
    int cc = t & 127, q = t >> 7;      // q in 0..3 -> rows q*4+rr
    float acc[4] = {0, 0, 0, 0};
    const float* wp = w + cc;
    for (int k = 0; k < EM; k += 4) {
        float w0 = wp[(k + 0) * EM], w1 = wp[(k + 1) * EM];
        float w2 = wp[(k + 2) * EM], w3 = wp[(k + 3) * EM];
        #pragma unroll
        for (int rr = 0; rr < 4; ++rr) {
            const float4 hv = *(const float4*)&hs[q * 4 + rr][k];
            acc[rr] = fmaf(hv.x, w0, fmaf(hv.y, w1, fmaf(hv.z, w2, fmaf(hv.w, w3, acc[rr]))));
        }
    }
    #pragma unroll
    for (int rr = 0; rr < 4; ++rr)
        hhb[(size_t)(row0 + q * 4 + rr) * EM + cc] = f2bf(acc[rr]);   // bf16 for PV
    __syncthreads();
    #pragma unroll
    for (int rr = 0; rr < 4; ++rr) hs[q * 4 + rr][cc] = acc[rr];      // fp32 for scores
    __syncthreads();
    if (t < 16 * NH) {
        int row = t >> 3, hd = t & 7;
        const float* ap = asrc + hd * HD;
        const float* dp = adst + hd * HD;
        float s1 = 0.f, s2 = 0.f;
        #pragma unroll
        for (int d = 0; d < HD; ++d) {
            float v = hs[row][hd * HD + d];
            s1 += v * ap[d]; s2 += v * dp[d];
        }
        ssrc[(size_t)(row0 + row) * NH + hd] = s1;
        sdst[(size_t)(row0 + row) * NH + hd] = s2;
    }
}

// ---- kernel 1: kNN (blocks 0..399)  ||  layer-0 mm (blocks 400..799) -------
__global__ __launch_bounds__(512) void k1_kernel(
        const float* __restrict__ pos, int* __restrict__ fwd,
        float* __restrict__ h, const float* __restrict__ x,
        const float* __restrict__ pw, const float* __restrict__ pb,
        const float* __restrict__ w0,
        const float* __restrict__ asrc0, const float* __restrict__ adst0,
        ushortx* __restrict__ hhb, float* __restrict__ ssrc, float* __restrict__ sdst,
        float* __restrict__ statz, float* __restrict__ out) {
    __shared__ float hs[16][EM];
    __shared__ int ctr[8];
    int bid = blockIdx.x;
    if (bid < KNB) {
        knn_radix(pos, fwd, bid, (float*)hs, ctr);
    } else {
        int tile = bid - KNB;
        if (tile == 0) {
            if (threadIdx.x < 256) statz[threadIdx.x * SPAD] = 0.f;
        } else if (tile == 1) {
            for (int idx = threadIdx.x; idx < BG * EM; idx += 512)
                out[(size_t)NN * EM + idx] = 0.f;   // zero graph-mean tail
        }
        mm_tile(tile, h, nullptr, nullptr, nullptr, nullptr,
                x, pw, pb, w0, asrc0, adst0, hhb, ssrc, sdst, hs);
    }
}

// ---- mm kernel for layers 1,2 (zeroes next stat accumulator) ---------------
__global__ __launch_bounds__(512) void mm_kernel(
        float* __restrict__ h, const float* __restrict__ gout,
        const float* __restrict__ stat, const float* __restrict__ gamma,
        const float* __restrict__ beta, const float* __restrict__ w,
        const float* __restrict__ asrc, const float* __restrict__ adst,
        ushortx* __restrict__ hhb, float* __restrict__ ssrc, float* __restrict__ sdst,
        float* __restrict__ statz) {
    __shared__ float hs[16][EM];
    if (blockIdx.x == 0 && threadIdx.x < 256) statz[threadIdx.x * SPAD] = 0.f;
    mm_tile(blockIdx.x, h, gout, stat, gamma, beta,
            nullptr, nullptr, nullptr, w, asrc, adst, hhb, ssrc, sdst, hs);
}

// ---- attention: 16 nodes/block, LDS ssrc table; FIRST builds adjacency -----
template<int FIRST>
__global__ __launch_bounds__(512) void attn_kernel(const ushortx* __restrict__ hhb,
                                                   const int* __restrict__ fwd,
                                                   const float* __restrict__ ssrc,
                                                   const float* __restrict__ sdst,
                                                   const float* __restrict__ bias,
                                                   float* __restrict__ gout,
                                                   float* __restrict__ statl,
                                                   int* __restrict__ nbrg,
                                                   int* __restrict__ cntg) {
    __shared__ float sc[8 * 1024];            // per-wave score slab [jj*8+hd]
    __shared__ int   nb[16][MAXDEG];          // graph-LOCAL neighbor ids (8 KB)
    __shared__ int cnt16[16];
    __shared__ float red[256];
    __shared__ float ssl[NPG * NH];           // graph's ssrc table (12.5 KB)
    int t = threadIdx.x, wv = t >> 6, lane = t & 63;
    int bid = blockIdx.x;
    int g = bid / 25;                          // 25 blocks per graph (400/16)
    int r0g = (bid - g * 25) * 16;             // graph-local row base
    int sbase = g * NPG;

    if (t < 256) red[t] = 0.f;
    // stage ssrc for the whole graph (coalesced float4)
    for (int idx = t; idx < NPG * NH / 4; idx += 512)
        ((float4*)ssl)[idx] = ((const float4*)(ssrc + (size_t)sbase * NH))[idx];
    int cA, cB;

    if (FIRST) {
        __shared__ unsigned bm[16][16];       // 16 rows x 512-bit adjacency
        __shared__ unsigned short roff[16][13];
        if (t < 256) ((unsigned*)bm)[t] = 0u;
        __syncthreads();
        const int* fg = fwd + (size_t)sbase * KNN;
        for (int e = t; e < NPG * KNN; e += 512) {
            int src = e / KNN;                 // graph-local
            int dst = fg[e];                   // graph-local
            int rs = src - r0g, rd = dst - r0g;
            if ((unsigned)rs < 16u) atomicOr(&bm[rs][dst >> 5], 1u << (dst & 31));
            if ((unsigned)rd < 16u) atomicOr(&bm[rd][src >> 5], 1u << (src & 31));
        }
        if (t < 16) atomicOr(&bm[t][(r0g + t) >> 5], 1u << ((r0g + t) & 31));  // self
        __syncthreads();
        if (t < 16) {                          // prefix popcounts per row
            int off = 0;
            #pragma unroll
            for (int w = 0; w < 13; ++w) { roff[t][w] = (unsigned short)off; off += __popc(bm[t][w]); }
            cnt16[t] = off < MAXDEG ? off : MAXDEG;
            cntg[bid * 16 + t] = cnt16[t];
        }
        __syncthreads();
        if (t < 16 * 13) {                     // (row,word) emit tasks
            int row = t / 13, w = t - row * 13;
            unsigned m = bm[row][w];
            int c = roff[row][w];
            int jb = w * 32;
            while (m) {
                int b = __ffs(m) - 1;
                m &= m - 1;
                if (c < MAXDEG) nb[row][c++] = jb + b;
            }
        }
        __syncthreads();
        // persist for layers 1,2 (coalesced; wave wv owns rows 2wv, 2wv+1)
        #pragma unroll
        for (int r2 = 0; r2 < 2; ++r2) {
            int row = wv * 2 + r2;
            int c = cnt16[row];
            int* dst = nbrg + ((size_t)bid * 16 + row) * MAXDEG;
            for (int j = lane; j < c; j += 64) dst[j] = nb[row][j];
        }
        cA = cnt16[wv * 2];
        cB = cnt16[wv * 2 + 1];
    } else {
        // per-wave: each wave only touches its own 2 rows -> single block sync
        cA = cntg[bid * 16 + wv * 2];          // broadcast scalar loads
        cB = cntg[bid * 16 + wv * 2 + 1];
        const int* srcA = nbrg + ((size_t)bid * 16 + wv * 2) * MAXDEG;
        const int* srcB = srcA + MAXDEG;
        for (int j = lane; j < cA; j += 64) nb[wv * 2][j] = srcA[j];
        for (int j = lane; j < cB; j += 64) nb[wv * 2 + 1][j] = srcB[j];
        __syncthreads();                       // orders red zero + ssl staging
    }

    float* scw = sc + wv * 1024;
    int hd = lane & 7, sub = lane >> 3, h0 = lane >> 3;
    float s1a = 0.f, s2a = 0.f, s1b = 0.f, s2b = 0.f;
    int iA = bid * 16 + wv * 2;
    float sdA = sdst[iA * NH + hd];            // hoisted independent loads
    float sdB = sdst[(iA + 1) * NH + hd];
    float2 bv = *(const float2*)(bias + 2 * lane);

    #pragma unroll 1
    for (int r2 = 0; r2 < 2; ++r2) {
        int nlo = wv * 2 + r2;                 // block-local node
        int i = iA + r2;                       // global node
        int c = r2 ? cB : cA;
        float sd = r2 ? sdB : sdA;
        int cp = (c + 7) & ~7;                 // pad to x8 for PV unroll
        if (lane < cp - c) nb[nlo][c + lane] = r0g + nlo;   // valid (self) pad ids

        for (int idx = lane; idx < cp * NH; idx += 64) {    // idx&7 == lane&7
            int jj = idx >> 3;
            float v = 0.f;
            if (jj < c) {
                v = sd + ssl[nb[nlo][jj] * NH + hd];        // LDS gather
                v = v >= 0.f ? v : NEGS * v;   // leaky_relu
            }
            scw[idx] = v;                      // pads = 0 (PV no-op)
        }
        asm volatile("s_waitcnt lgkmcnt(0)" ::: "memory");
        float mx = -INFINITY;
        for (int jj = sub; jj < c; jj += 8) mx = fmaxf(mx, scw[jj * 8 + hd]);
        #pragma unroll
        for (int off = 8; off < 64; off <<= 1) mx = fmaxf(mx, __shfl_xor(mx, off));
        float s = 0.f;
        for (int jj = sub; jj < c; jj += 8) {
            float e = __expf(scw[jj * 8 + hd] - mx);
            scw[jj * 8 + hd] = e;
            s += e;
        }
        #pragma unroll
        for (int off = 8; off < 64; off <<= 1) s += __shfl_xor(s, off);
        float inv = 1.f / s;                   // lane k (k<8) holds inv for head k
        asm volatile("s_waitcnt lgkmcnt(0)" ::: "memory");

        // PV: lane owns channels (2*lane, 2*lane+1); 8 outstanding gathers
        float invh = __shfl(inv, h0);
        const unsigned* hp32 = (const unsigned*)hhb;
        float acc0 = 0.f, acc1 = 0.f;
        for (int jj = 0; jj < cp; jj += 8) {
            float a0 = scw[(jj + 0) * 8 + h0];
            float a1 = scw[(jj + 1) * 8 + h0];
            float a2 = scw[(jj + 2) * 8 + h0];
            float a3 = scw[(jj + 3) * 8 + h0];
            float a4 = scw[(jj + 4) * 8 + h0];
            float a5 = scw[(jj + 5) * 8 + h0];
            float a6 = scw[(jj + 6) * 8 + h0];
            float a7 = scw[(jj + 7) * 8 + h0];
            unsigned u0 = hp32[(size_t)(sbase + nb[nlo][jj + 0]) * 64 + lane];
            unsigned u1 = hp32[(size_t)(sbase + nb[nlo][jj + 1]) * 64 + lane];
            unsigned u2 = hp32[(size_t)(sbase + nb[nlo][jj + 2]) * 64 + lane];
            unsigned u3 = hp32[(size_t)(sbase + nb[nlo][jj + 3]) * 64 + lane];
            unsigned u4 = hp32[(size_t)(sbase + nb[nlo][jj + 4]) * 64 + lane];
            unsigned u5 = hp32[(size_t)(sbase + nb[nlo][jj + 5]) * 64 + lane];
            unsigned u6 = hp32[(size_t)(sbase + nb[nlo][jj + 6]) * 64 + lane];
            unsigned u7 = hp32[(size_t)(sbase + nb[nlo][jj + 7]) * 64 + lane];
            acc0 += a0 * __uint_as_float(u0 << 16) + a1 * __uint_as_float(u1 << 16)
                  + a2 * __uint_as_float(u2 << 16) + a3 * __uint_as_float(u3 << 16);
            acc1 += a0 * __uint_as_float(u0 & 0xFFFF0000u) + a1 * __uint_as_float(u1 & 0xFFFF0000u)
                  + a2 * __uint_as_float(u2 & 0xFFFF0000u) + a3 * __uint_as_float(u3 & 0xFFFF0000u);
            acc0 += a4 * __uint_as_float(u4 << 16) + a5 * __uint_as_float(u5 << 16)
                  + a6 * __uint_as_float(u6 << 16) + a7 * __uint_as_float(u7 << 16);
            acc1 += a4 * __uint_as_float(u4 & 0xFFFF0000u) + a5 * __uint_as_float(u5 & 0xFFFF0000u)
                  + a6 * __uint_as_float(u6 & 0xFFFF0000u) + a7 * __uint_as_float(u7 & 0xFFFF0000u);
        }
        float v0 = acc0 * invh + bv.x;
        float v1 = acc1 * invh + bv.y;
        float2 ov; ov.x = v0; ov.y = v1;
        *(float2*)(gout + (size_t)i * EM + 2 * lane) = ov;
        s1a += v0; s2a += v0 * v0;
        s1b += v1; s2b += v1 * v1;
    }

    // BN stat partials: channels 2*lane (a), 2*lane+1 (b); one pass for 2 nodes
    atomicAdd(&red[2 * lane], s1a);
    atomicAdd(&red[2 * lane + 1], s1b);
    atomicAdd(&red[128 + 2 * lane], s2a);
    atomicAdd(&red[128 + 2 * lane + 1], s2b);
    __syncthreads();
    if (t < 256)
        atomicAdd(&statl[t * SPAD], red[t]);
}

// ---- final: BN+ELU+residual (layer 2) -> node out + graph-mean atomics -----
__global__ __launch_bounds__(512) void finish_kernel(const float* __restrict__ gout,
                                                     const float* __restrict__ stat,
                                                     const float* __restrict__ gamma,
                                                     const float* __restrict__ beta,
                                                     const float* __restrict__ h,
                                                     float* __restrict__ out) {
    int bid = blockIdx.x;        // 400 blocks x 16 rows (25 blocks per graph)
    int g = bid / 25;
    int row0 = bid * 16;
    int t = threadIdx.x, c = t & 127;
    float m  = stat[c * SPAD] * (1.f / NN);
    float vr = stat[(128 + c) * SPAD] * (1.f / NN) - m * m;
    float rs = rsqrtf(vr + BNEPS);
    float ga = gamma[c], be = beta[c];
    float s = 0.f;
    #pragma unroll
    for (int k = 0; k < 4; ++k) {
        int idx = k * 512 + t;               // c stays t&127; row = k*4 + (t>>7)
        int r = idx >> 7;
        size_t gi = (size_t)(row0 + r) * EM + c;
        float v = (gout[gi] - m) * rs * ga + be;
        v = v > 0.f ? v : __expf(v) - 1.f;
        v += h[gi];
        out[gi] = v;
        s += v;
    }
    __shared__ float l1[512];
    l1[t] = s;
    __syncthreads();
    if (t < 128)
        atomicAdd(&out[(size_t)NN * EM + g * EM + t],
                  (l1[t] + l1[t + 128] + l1[t + 256] + l1[t + 384]) * (1.f / NPG));
}

extern "C" void kernel_launch(void* const* d_in, const int* in_sizes, int n_in,
                              void* d_out, int out_size, void* d_ws, size_t ws_size,
                              hipStream_t stream) {
    const float* x      = (const float*)d_in[0];
    const float* pos    = (const float*)d_in[1];
    // d_in[2] = batch (int32), unused: graphs are contiguous blocks of 400
    const float* proj_w = (const float*)d_in[3];
    const float* proj_b = (const float*)d_in[4];
    const float* lin_w  = (const float*)d_in[5];
    const float* asrc   = (const float*)d_in[6];
    const float* adst   = (const float*)d_in[7];
    const float* gbias  = (const float*)d_in[8];
    const float* gamma  = (const float*)d_in[9];
    const float* beta   = (const float*)d_in[10];
    float* out = (float*)d_out;

    char* p = (char*)d_ws;
    auto take = [&](size_t bytes) { char* q = p; p += (bytes + 63) & ~(size_t)63; return q; };
    int*     fwd  = (int*)take((size_t)NN * KNN * 4);
    int*     nbrg = (int*)take((size_t)NN * MAXDEG * 4);
    int*     cntg = (int*)take((size_t)NN * 4);
    float*   h    = (float*)take((size_t)NN * EM * 4);
    ushortx* hhb  = (ushortx*)take((size_t)NN * EM * 2);
    float*   gout = (float*)take((size_t)NN * EM * 4);
    float*   ssrc = (float*)take((size_t)NN * NH * 4);
    float*   sdst = (float*)take((size_t)NN * NH * 4);
    float*   statA = (float*)take((size_t)256 * SPAD * 4);
    float*   statB = (float*)take((size_t)256 * SPAD * 4);
    float*   statv[2] = {statA, statB};

    // 1: kNN (radix, 2 nodes/wave, LDS pos) || layer-0 mm (+zero stat, tail)
    k1_kernel<<<KNB + MMB, 512, 0, stream>>>(pos, fwd, h, x, proj_w, proj_b,
                                             lin_w, asrc, adst, hhb, ssrc, sdst,
                                             statv[0], out);
    // 2: attn layer 0 (builds + persists adjacency) -> statv[0]
    attn_kernel<1><<<ANB, 512, 0, stream>>>(hhb, fwd, ssrc, sdst, gbias, gout,
                                            statv[0], nbrg, cntg);
    // 3: mm layer 1 (reads statv[0], zeroes statv[1])
    mm_kernel<<<MMB, 512, 0, stream>>>(h, gout, statv[0], gamma, beta,
                                       lin_w + (size_t)EM * EM, asrc + EM, adst + EM,
                                       hhb, ssrc, sdst, statv[1]);
    // 4: attn layer 1 (loads adjacency per-wave) -> statv[1]
    attn_kernel<0><<<ANB, 512, 0, stream>>>(hhb, fwd, ssrc, sdst, gbias + EM, gout,
                                            statv[1], nbrg, cntg);
    // 5: mm layer 2 (reads statv[1], zeroes statv[0])
    mm_kernel<<<MMB, 512, 0, stream>>>(h, gout, statv[1], gamma + EM, beta + EM,
                                       lin_w + (size_t)2 * EM * EM, asrc + 2 * EM, adst + 2 * EM,
                                       hhb, ssrc, sdst, statv[0]);
    // 6: attn layer 2 (loads adjacency per-wave) -> statv[0]
    attn_kernel<0><<<ANB, 512, 0, stream>>>(hhb, fwd, ssrc, sdst, gbias + 2 * EM, gout,
                                            statv[0], nbrg, cntg);
    // 7: finish (400 blocks, matches mm tiling)
    finish_kernel<<<MMB, 512, 0, stream>>>(gout, statv[0],
                                           gamma + 2 * EM, beta + 2 * EM, h, out);
}

// Round 20
// 111.791 us; speedup vs baseline: 1.1816x; 1.0531x over previous
//
#include <hip/hip_runtime.h>
#include <math.h>

#define BG   16
#define NPG  400
#define NN   (BG*NPG)      // 6400 nodes
#define KNN  20
#define NH   8
#define HD   16
#define EM   128
#define NL   3
#define NEGS 0.2f
#define BNEPS 1e-5f
#define MAXDEG 128
#define NSLOT 7            // ceil(400/64) candidates per lane
#define SPAD 4             // floats per BN-stat slot (16B padding)
#define NSTK 8             // stat banks (8-way contention split)
#define STSZ (NSTK*256*SPAD)
#define KNB  400           // knn blocks (8 waves x 2 nodes = 16 nodes each)
#define MMB  400           // mm tiles (16 rows each, 512 threads)
#define ANB  (NN/16)       // attn blocks: 16 nodes each (8 waves x 2 nodes serial)

typedef unsigned short ushortx;

__device__ __forceinline__ ushortx f2bf(float x) {   // round-to-nearest-even bf16
    unsigned b = __float_as_uint(x);
    return (ushortx)((b + 0x7FFFu + ((b >> 16) & 1u)) >> 16);
}

// sum the 8 stat banks for entry e (e in 0..255)
__device__ __forceinline__ float stat_sum(const float* __restrict__ stat, int e) {
    float s = 0.f;
    #pragma unroll
    for (int k = 0; k < NSTK; ++k) s += stat[(k * 256 + e) * SPAD];
    return s;
}

// --- kNN: wave per 2 nodes, RADIX-SELECT top-20, LDS-staged positions -------
__device__ __forceinline__ void knn_radix(const float* __restrict__ pos,
                                          int* __restrict__ fwd, int bid,
                                          float* __restrict__ ps,   // >= 800 floats LDS
                                          int* __restrict__ ctr) {
    int wave = threadIdx.x >> 6, lane = threadIdx.x & 63;
    int g = bid / 25;                   // 25 blocks per graph (16 nodes each)
    const float* pg = pos + (size_t)g * NPG * 2;
    for (int idx = threadIdx.x; idx < NPG * 2; idx += 512) ps[idx] = pg[idx];
    __syncthreads();

    #pragma unroll 1
    for (int r2 = 0; r2 < 2; ++r2) {
        int i = bid * 16 + wave * 2 + r2;   // global node
        int li = i - g * NPG;               // graph-local index
        float xi = ps[li * 2], yi = ps[li * 2 + 1];

        unsigned kk[NSLOT], kx[NSLOT];      // key bits; key ^ selected-prefix
        #pragma unroll
        for (int s = 0; s < NSLOT; ++s) {
            int j = lane + (s << 6);
            unsigned kb = 0x7F800000u;      // +inf for invalid/self
            if (j < NPG && j != li) {
                float dx = __fsub_rn(xi, ps[j * 2]);
                float dy = __fsub_rn(yi, ps[j * 2 + 1]);
                float d2 = __fadd_rn(__fmul_rn(dx, dx), __fmul_rn(dy, dy));  // exact np rounding
                kb = __float_as_uint(d2);
            }
            kk[s] = kb; kx[s] = kb;
        }

        // MSB radix select: P = 20th-smallest key; R = #needed among ==P
        unsigned P = 0; int R = KNN;
        #pragma unroll
        for (int bit = 29; bit >= 0; --bit) {
            int c = 0;
            #pragma unroll
            for (int s = 0; s < NSLOT; ++s)
                c += __popcll(__ballot(kx[s] < (1u << bit)));   // prefix-match AND bit==0
            unsigned delta = (R > c) ? (1u << bit) : 0u;
            R -= (R > c) ? c : 0;
            P |= delta;
            #pragma unroll
            for (int s = 0; s < NSLOT; ++s) kx[s] ^= delta;
        }

        bool sel[NSLOT];
        int nsel = 0;
        #pragma unroll
        for (int s = 0; s < NSLOT; ++s) { sel[s] = kk[s] < P; nsel += sel[s] ? 1 : 0; }

        // threshold keys (kx==0 <=> kk==P): fast path when no tie competition
        int ceq = 0;
        #pragma unroll
        for (int s = 0; s < NSLOT; ++s) ceq += __popcll(__ballot(kx[s] == 0u));
        if (ceq == R) {
            #pragma unroll
            for (int s = 0; s < NSLOT; ++s)
                if (kx[s] == 0u) { sel[s] = true; nsel++; }
            R = 0;
        }
        #pragma unroll 1
        while (R > 0) {                 // rare: ties at threshold, take smallest j
            int bj = 0x7FFFFFFF;
            #pragma unroll
            for (int s = 0; s < NSLOT; ++s)
                if (kx[s] == 0 && !sel[s]) { int j = lane + (s << 6); bj = j < bj ? j : bj; }
            int m = bj;
            #pragma unroll
            for (int off = 32; off > 0; off >>= 1) { int o = __shfl_xor(m, off); m = o < m ? o : m; }
            if (bj == m && bj != 0x7FFFFFFF) {
                #pragma unroll
                for (int s = 0; s < NSLOT; ++s)
                    if ((lane + (s << 6)) == bj) { sel[s] = true; nsel++; }
            }
            R--;
        }

        // emit (order-free set); per-wave LDS counter (wave-lockstep safe)
        if (lane == 0) ctr[wave] = 0;
        int pos0 = atomicAdd(&ctr[wave], nsel);
        int w = 0;
        #pragma unroll
        for (int s = 0; s < NSLOT; ++s)
            if (sel[s]) { fwd[(size_t)i * KNN + pos0 + w] = lane + (s << 6); ++w; }
    }
}

// ---- mm tile (16 rows, 512 thr): [proj | BN+ELU+res] + hh(bf16) + scores ---
__device__ __forceinline__ void mm_tile(
        int tile, float* __restrict__ h, const float* __restrict__ gout,
        const float* __restrict__ stat, const float* __restrict__ gamma,
        const float* __restrict__ beta, const float* __restrict__ x,
        const float* __restrict__ pw, const float* __restrict__ pb,
        const float* __restrict__ w,
        const float* __restrict__ asrc, const float* __restrict__ adst,
        ushortx* __restrict__ hhb, float* __restrict__ ssrc, float* __restrict__ sdst,
        float (*hs)[EM]) {
    int t = threadIdx.x;               // 0..511
    int row0 = tile * 16;
    int cc0 = t & 127;
    float m = 0.f, rsd = 0.f, ga = 0.f, be = 0.f;
    if (gout) {                        // per-thread channel is fixed (t&127)
        m = stat_sum(stat, cc0) * (1.f / NN);
        float vr = stat_sum(stat, 128 + cc0) * (1.f / NN) - m * m;
        rsd = rsqrtf(vr + BNEPS);
        ga = gamma[cc0]; be = beta[cc0];
    }
    for (int idx = t; idx < 16 * EM; idx += 512) {
        int r = idx >> 7, c = idx & 127;   // c == cc0 (stride 512 preserves low7)
        size_t gi = (size_t)(row0 + r) * EM + c;
        float v;
        if (gout) {
            float bnv = (gout[gi] - m) * rsd * ga + be;
            bnv = bnv > 0.f ? bnv : __expf(bnv) - 1.f;   // elu (fast exp)
            v = bnv + h[gi];                        // residual
        } else {
            int n = row0 + r;                       // input projection
            v = x[n * 3 + 0] * pw[c] + x[n * 3 + 1] * pw[EM + c]
              + x[n * 3 + 2] * pw[2 * EM + c] + pb[c];
        }
        h[gi] = v;
        hs[r][c] = v;
    }
    __syncthreads();
    int cc = t & 127, q = t >> 7;      // q in 0..3 -> rows q*4+rr
    float acc[4] = {0, 0, 0, 0};
    const float* wp = w + cc;
    for (int k = 0; k < EM; k += 4) {
        float w0 = wp[(k + 0) * EM], w1 = wp[(k + 1) * EM];
        float w2 = wp[(k + 2) * EM], w3 = wp[(k + 3) * EM];
        #pragma unroll
        for (int rr = 0; rr < 4; ++rr) {
            const float4 hv = *(const float4*)&hs[q * 4 + rr][k];
            acc[rr] = fmaf(hv.x, w0, fmaf(hv.y, w1, fmaf(hv.z, w2, fmaf(hv.w, w3, acc[rr]))));
        }
    }
    #pragma unroll
    for (int rr = 0; rr < 4; ++rr)
        hhb[(size_t)(row0 + q * 4 + rr) * EM + cc] = f2bf(acc[rr]);   // bf16 for PV
    __syncthreads();
    #pragma unroll
    for (int rr = 0; rr < 4; ++rr) hs[q * 4 + rr][cc] = acc[rr];      // fp32 for scores
    __syncthreads();
    if (t < 16 * NH) {
        int row = t >> 3, hd = t & 7;
        const float* ap = asrc + hd * HD;
        const float* dp = adst + hd * HD;
        float s1 = 0.f, s2 = 0.f;
        #pragma unroll
        for (int d = 0; d < HD; ++d) {
            float v = hs[row][hd * HD + d];
            s1 += v * ap[d]; s2 += v * dp[d];
        }
        ssrc[(size_t)(row0 + row) * NH + hd] = s1;
        sdst[(size_t)(row0 + row) * NH + hd] = s2;
    }
}

// ---- kernel 1: kNN (blocks 0..399)  ||  layer-0 mm (blocks 400..799) -------
__global__ __launch_bounds__(512) void k1_kernel(
        const float* __restrict__ pos, int* __restrict__ fwd,
        float* __restrict__ h, const float* __restrict__ x,
        const float* __restrict__ pw, const float* __restrict__ pb,
        const float* __restrict__ w0,
        const float* __restrict__ asrc0, const float* __restrict__ adst0,
        ushortx* __restrict__ hhb, float* __restrict__ ssrc, float* __restrict__ sdst,
        float* __restrict__ statz, float* __restrict__ out) {
    __shared__ float hs[16][EM];
    __shared__ int ctr[8];
    int bid = blockIdx.x;
    if (bid < KNB) {
        knn_radix(pos, fwd, bid, (float*)hs, ctr);
    } else {
        int tile = bid - KNB;
        if (tile == 0) {
            #pragma unroll
            for (int k = 0; k < NSTK * 256 / 512; ++k)
                statz[(k * 512 + threadIdx.x) * SPAD] = 0.f;
        } else if (tile == 1) {
            for (int idx = threadIdx.x; idx < BG * EM; idx += 512)
                out[(size_t)NN * EM + idx] = 0.f;   // zero graph-mean tail
        }
        mm_tile(tile, h, nullptr, nullptr, nullptr, nullptr,
                x, pw, pb, w0, asrc0, adst0, hhb, ssrc, sdst, hs);
    }
}

// ---- mm kernel for layers 1,2 (zeroes next stat accumulator) ---------------
__global__ __launch_bounds__(512) void mm_kernel(
        float* __restrict__ h, const float* __restrict__ gout,
        const float* __restrict__ stat, const float* __restrict__ gamma,
        const float* __restrict__ beta, const float* __restrict__ w,
        const float* __restrict__ asrc, const float* __restrict__ adst,
        ushortx* __restrict__ hhb, float* __restrict__ ssrc, float* __restrict__ sdst,
        float* __restrict__ statz) {
    __shared__ float hs[16][EM];
    if (blockIdx.x == 0) {
        #pragma unroll
        for (int k = 0; k < NSTK * 256 / 512; ++k)
            statz[(k * 512 + threadIdx.x) * SPAD] = 0.f;
    }
    mm_tile(blockIdx.x, h, gout, stat, gamma, beta,
            nullptr, nullptr, nullptr, w, asrc, adst, hhb, ssrc, sdst, hs);
}

// ---- attention: 16 nodes/block, LDS ssrc table; FIRST builds adjacency -----
template<int FIRST>
__global__ __launch_bounds__(512) void attn_kernel(const ushortx* __restrict__ hhb,
                                                   const int* __restrict__ fwd,
                                                   const float* __restrict__ ssrc,
                                                   const float* __restrict__ sdst,
                                                   const float* __restrict__ bias,
                                                   float* __restrict__ gout,
                                                   float* __restrict__ statl,
                                                   int* __restrict__ nbrg,
                                                   int* __restrict__ cntg) {
    __shared__ float sc[8 * 1024];            // per-wave score slab [jj*8+hd]
    __shared__ int   nb[16][MAXDEG];          // graph-LOCAL neighbor ids (8 KB)
    __shared__ int cnt16[16];
    __shared__ float red[256];
    __shared__ float ssl[NPG * NH];           // graph's ssrc table (12.5 KB)
    int t = threadIdx.x, wv = t >> 6, lane = t & 63;
    int bid = blockIdx.x;
    int g = bid / 25;                          // 25 blocks per graph (400/16)
    int r0g = (bid - g * 25) * 16;             // graph-local row base
    int sbase = g * NPG;

    if (t < 256) red[t] = 0.f;
    // stage ssrc for the whole graph (coalesced float4)
    for (int idx = t; idx < NPG * NH / 4; idx += 512)
        ((float4*)ssl)[idx] = ((const float4*)(ssrc + (size_t)sbase * NH))[idx];
    int cA, cB;

    if (FIRST) {
        __shared__ unsigned bm[16][16];       // 16 rows x 512-bit adjacency
        __shared__ unsigned short roff[16][13];
        if (t < 256) ((unsigned*)bm)[t] = 0u;
        __syncthreads();
        const int* fg = fwd + (size_t)sbase * KNN;
        for (int e = t; e < NPG * KNN; e += 512) {
            int src = e / KNN;                 // graph-local
            int dst = fg[e];                   // graph-local
            int rs = src - r0g, rd = dst - r0g;
            if ((unsigned)rs < 16u) atomicOr(&bm[rs][dst >> 5], 1u << (dst & 31));
            if ((unsigned)rd < 16u) atomicOr(&bm[rd][src >> 5], 1u << (src & 31));
        }
        if (t < 16) atomicOr(&bm[t][(r0g + t) >> 5], 1u << ((r0g + t) & 31));  // self
        __syncthreads();
        if (t < 16) {                          // prefix popcounts per row
            int off = 0;
            #pragma unroll
            for (int w = 0; w < 13; ++w) { roff[t][w] = (unsigned short)off; off += __popc(bm[t][w]); }
            cnt16[t] = off < MAXDEG ? off : MAXDEG;
            cntg[bid * 16 + t] = cnt16[t];
        }
        __syncthreads();
        if (t < 16 * 13) {                     // (row,word) emit tasks
            int row = t / 13, w = t - row * 13;
            unsigned m = bm[row][w];
            int c = roff[row][w];
            int jb = w * 32;
            while (m) {
                int b = __ffs(m) - 1;
                m &= m - 1;
                if (c < MAXDEG) nb[row][c++] = jb + b;
            }
        }
        __syncthreads();
        // persist for layers 1,2 (coalesced; wave wv owns rows 2wv, 2wv+1)
        #pragma unroll
        for (int r2 = 0; r2 < 2; ++r2) {
            int row = wv * 2 + r2;
            int c = cnt16[row];
            int* dst = nbrg + ((size_t)bid * 16 + row) * MAXDEG;
            for (int j = lane; j < c; j += 64) dst[j] = nb[row][j];
        }
        cA = cnt16[wv * 2];
        cB = cnt16[wv * 2 + 1];
    } else {
        // per-wave: each wave only touches its own 2 rows -> single block sync
        cA = cntg[bid * 16 + wv * 2];          // broadcast scalar loads
        cB = cntg[bid * 16 + wv * 2 + 1];
        const int* srcA = nbrg + ((size_t)bid * 16 + wv * 2) * MAXDEG;
        const int* srcB = srcA + MAXDEG;
        for (int j = lane; j < cA; j += 64) nb[wv * 2][j] = srcA[j];
        for (int j = lane; j < cB; j += 64) nb[wv * 2 + 1][j] = srcB[j];
        __syncthreads();                       // orders red zero + ssl staging
    }

    float* scw = sc + wv * 1024;
    int hd = lane & 7, sub = lane >> 3, h0 = lane >> 3;
    float s1a = 0.f, s2a = 0.f, s1b = 0.f, s2b = 0.f;
    int iA = bid * 16 + wv * 2;
    float sdA = sdst[iA * NH + hd];            // hoisted independent loads
    float sdB = sdst[(iA + 1) * NH + hd];
    float2 bv = *(const float2*)(bias + 2 * lane);

    #pragma unroll 1
    for (int r2 = 0; r2 < 2; ++r2) {
        int nlo = wv * 2 + r2;                 // block-local node
        int i = iA + r2;                       // global node
        int c = r2 ? cB : cA;
        float sd = r2 ? sdB : sdA;
        int cp = (c + 7) & ~7;                 // pad to x8 for PV unroll
        if (lane < cp - c) nb[nlo][c + lane] = r0g + nlo;   // valid (self) pad ids

        for (int idx = lane; idx < cp * NH; idx += 64) {    // idx&7 == lane&7
            int jj = idx >> 3;
            float v = 0.f;
            if (jj < c) {
                v = sd + ssl[nb[nlo][jj] * NH + hd];        // LDS gather
                v = v >= 0.f ? v : NEGS * v;   // leaky_relu
            }
            scw[idx] = v;                      // pads = 0 (PV no-op)
        }
        asm volatile("s_waitcnt lgkmcnt(0)" ::: "memory");
        float mx = -INFINITY;
        for (int jj = sub; jj < c; jj += 8) mx = fmaxf(mx, scw[jj * 8 + hd]);
        #pragma unroll
        for (int off = 8; off < 64; off <<= 1) mx = fmaxf(mx, __shfl_xor(mx, off));
        float s = 0.f;
        for (int jj = sub; jj < c; jj += 8) {
            float e = __expf(scw[jj * 8 + hd] - mx);
            scw[jj * 8 + hd] = e;
            s += e;
        }
        #pragma unroll
        for (int off = 8; off < 64; off <<= 1) s += __shfl_xor(s, off);
        float inv = 1.f / s;                   // lane k (k<8) holds inv for head k
        asm volatile("s_waitcnt lgkmcnt(0)" ::: "memory");

        // PV: lane owns channels (2*lane, 2*lane+1); 8 outstanding gathers
        float invh = __shfl(inv, h0);
        const unsigned* hp32 = (const unsigned*)hhb;
        float acc0 = 0.f, acc1 = 0.f;
        for (int jj = 0; jj < cp; jj += 8) {
            float a0 = scw[(jj + 0) * 8 + h0];
            float a1 = scw[(jj + 1) * 8 + h0];
            float a2 = scw[(jj + 2) * 8 + h0];
            float a3 = scw[(jj + 3) * 8 + h0];
            float a4 = scw[(jj + 4) * 8 + h0];
            float a5 = scw[(jj + 5) * 8 + h0];
            float a6 = scw[(jj + 6) * 8 + h0];
            float a7 = scw[(jj + 7) * 8 + h0];
            unsigned u0 = hp32[(size_t)(sbase + nb[nlo][jj + 0]) * 64 + lane];
            unsigned u1 = hp32[(size_t)(sbase + nb[nlo][jj + 1]) * 64 + lane];
            unsigned u2 = hp32[(size_t)(sbase + nb[nlo][jj + 2]) * 64 + lane];
            unsigned u3 = hp32[(size_t)(sbase + nb[nlo][jj + 3]) * 64 + lane];
            unsigned u4 = hp32[(size_t)(sbase + nb[nlo][jj + 4]) * 64 + lane];
            unsigned u5 = hp32[(size_t)(sbase + nb[nlo][jj + 5]) * 64 + lane];
            unsigned u6 = hp32[(size_t)(sbase + nb[nlo][jj + 6]) * 64 + lane];
            unsigned u7 = hp32[(size_t)(sbase + nb[nlo][jj + 7]) * 64 + lane];
            acc0 += a0 * __uint_as_float(u0 << 16) + a1 * __uint_as_float(u1 << 16)
                  + a2 * __uint_as_float(u2 << 16) + a3 * __uint_as_float(u3 << 16);
            acc1 += a0 * __uint_as_float(u0 & 0xFFFF0000u) + a1 * __uint_as_float(u1 & 0xFFFF0000u)
                  + a2 * __uint_as_float(u2 & 0xFFFF0000u) + a3 * __uint_as_float(u3 & 0xFFFF0000u);
            acc0 += a4 * __uint_as_float(u4 << 16) + a5 * __uint_as_float(u5 << 16)
                  + a6 * __uint_as_float(u6 << 16) + a7 * __uint_as_float(u7 << 16);
            acc1 += a4 * __uint_as_float(u4 & 0xFFFF0000u) + a5 * __uint_as_float(u5 & 0xFFFF0000u)
                  + a6 * __uint_as_float(u6 & 0xFFFF0000u) + a7 * __uint_as_float(u7 & 0xFFFF0000u);
        }
        float v0 = acc0 * invh + bv.x;
        float v1 = acc1 * invh + bv.y;
        float2 ov; ov.x = v0; ov.y = v1;
        *(float2*)(gout + (size_t)i * EM + 2 * lane) = ov;
        s1a += v0; s2a += v0 * v0;
        s1b += v1; s2b += v1 * v1;
    }

    // BN stat partials -> bank bid&7 (8-way contention split)
    atomicAdd(&red[2 * lane], s1a);
    atomicAdd(&red[2 * lane + 1], s1b);
    atomicAdd(&red[128 + 2 * lane], s2a);
    atomicAdd(&red[128 + 2 * lane + 1], s2b);
    __syncthreads();
    if (t < 256)
        atomicAdd(&statl[((bid & (NSTK - 1)) * 256 + t) * SPAD], red[t]);
}

// ---- final: BN+ELU+residual (layer 2) -> node out + graph-mean atomics -----
__global__ __launch_bounds__(512) void finish_kernel(const float* __restrict__ gout,
                                                     const float* __restrict__ stat,
                                                     const float* __restrict__ gamma,
                                                     const float* __restrict__ beta,
                                                     const float* __restrict__ h,
                                                     float* __restrict__ out) {
    int bid = blockIdx.x;        // 400 blocks x 16 rows (25 blocks per graph)
    int g = bid / 25;
    int row0 = bid * 16;
    int t = threadIdx.x, c = t & 127;
    float m  = stat_sum(stat, c) * (1.f / NN);
    float vr = stat_sum(stat, 128 + c) * (1.f / NN) - m * m;
    float rs = rsqrtf(vr + BNEPS);
    float ga = gamma[c], be = beta[c];
    float s = 0.f;
    #pragma unroll
    for (int k = 0; k < 4; ++k) {
        int idx = k * 512 + t;               // c stays t&127; row = k*4 + (t>>7)
        int r = idx >> 7;
        size_t gi = (size_t)(row0 + r) * EM + c;
        float v = (gout[gi] - m) * rs * ga + be;
        v = v > 0.f ? v : __expf(v) - 1.f;
        v += h[gi];
        out[gi] = v;
        s += v;
    }
    __shared__ float l1[512];
    l1[t] = s;
    __syncthreads();
    if (t < 128)
        atomicAdd(&out[(size_t)NN * EM + g * EM + t],
                  (l1[t] + l1[t + 128] + l1[t + 256] + l1[t + 384]) * (1.f / NPG));
}

extern "C" void kernel_launch(void* const* d_in, const int* in_sizes, int n_in,
                              void* d_out, int out_size, void* d_ws, size_t ws_size,
                              hipStream_t stream) {
    const float* x      = (const float*)d_in[0];
    const float* pos    = (const float*)d_in[1];
    // d_in[2] = batch (int32), unused: graphs are contiguous blocks of 400
    const float* proj_w = (const float*)d_in[3];
    const float* proj_b = (const float*)d_in[4];
    const float* lin_w  = (const float*)d_in[5];
    const float* asrc   = (const float*)d_in[6];
    const float* adst   = (const float*)d_in[7];
    const float* gbias  = (const float*)d_in[8];
    const float* gamma  = (const float*)d_in[9];
    const float* beta   = (const float*)d_in[10];
    float* out = (float*)d_out;

    char* p = (char*)d_ws;
    auto take = [&](size_t bytes) { char* q = p; p += (bytes + 63) & ~(size_t)63; return q; };
    int*     fwd  = (int*)take((size_t)NN * KNN * 4);
    int*     nbrg = (int*)take((size_t)NN * MAXDEG * 4);
    int*     cntg = (int*)take((size_t)NN * 4);
    float*   h    = (float*)take((size_t)NN * EM * 4);
    ushortx* hhb  = (ushortx*)take((size_t)NN * EM * 2);
    float*   gout = (float*)take((size_t)NN * EM * 4);
    float*   ssrc = (float*)take((size_t)NN * NH * 4);
    float*   sdst = (float*)take((size_t)NN * NH * 4);
    float*   statA = (float*)take((size_t)STSZ * 4);
    float*   statB = (float*)take((size_t)STSZ * 4);
    float*   statv[2] = {statA, statB};

    // 1: kNN (radix, 2 nodes/wave, LDS pos) || layer-0 mm (+zero stat, tail)
    k1_kernel<<<KNB + MMB, 512, 0, stream>>>(pos, fwd, h, x, proj_w, proj_b,
                                             lin_w, asrc, adst, hhb, ssrc, sdst,
                                             statv[0], out);
    // 2: attn layer 0 (builds + persists adjacency) -> statv[0] banks
    attn_kernel<1><<<ANB, 512, 0, stream>>>(hhb, fwd, ssrc, sdst, gbias, gout,
                                            statv[0], nbrg, cntg);
    // 3: mm layer 1 (reads statv[0], zeroes statv[1])
    mm_kernel<<<MMB, 512, 0, stream>>>(h, gout, statv[0], gamma, beta,
                                       lin_w + (size_t)EM * EM, asrc + EM, adst + EM,
                                       hhb, ssrc, sdst, statv[1]);
    // 4: attn layer 1 (loads adjacency per-wave) -> statv[1] banks
    attn_kernel<0><<<ANB, 512, 0, stream>>>(hhb, fwd, ssrc, sdst, gbias + EM, gout,
                                            statv[1], nbrg, cntg);
    // 5: mm layer 2 (reads statv[1], zeroes statv[0])
    mm_kernel<<<MMB, 512, 0, stream>>>(h, gout, statv[1], gamma + EM, beta + EM,
                                       lin_w + (size_t)2 * EM * EM, asrc + 2 * EM, adst + 2 * EM,
                                       hhb, ssrc, sdst, statv[0]);
    // 6: attn layer 2 (loads adjacency per-wave) -> statv[0] banks
    attn_kernel<0><<<ANB, 512, 0, stream>>>(hhb, fwd, ssrc, sdst, gbias + 2 * EM, gout,
                                            statv[0], nbrg, cntg);
    // 7: finish (400 blocks, matches mm tiling)
    finish_kernel<<<MMB, 512, 0, stream>>>(gout, statv[0],
                                           gamma + 2 * EM, beta + 2 * EM, h, out);
}

// Round 21
// 110.387 us; speedup vs baseline: 1.1966x; 1.0127x over previous
//
#include <hip/hip_runtime.h>
#include <math.h>

#define BG   16
#define NPG  400
#define NN   (BG*NPG)      // 6400 nodes
#define KNN  20
#define NH   8
#define HD   16
#define EM   128
#define NL   3
#define NEGS 0.2f
#define BNEPS 1e-5f
#define MAXDEG 128
#define NSLOT 7            // ceil(400/64) candidates per lane
#define SPAD 4             // floats per BN-stat slot (16B padding)
#define NSTK 8             // stat banks (8-way contention split)
#define STSZ (NSTK*256*SPAD)
#define KNB  400           // knn blocks (8 waves x 2 nodes = 16 nodes each)
#define MMB  400           // mm tiles (16 rows each, 512 threads)
#define ANB  (NN/16)       // attn blocks: 16 nodes each (8 waves x 2 nodes serial)

typedef unsigned short ushortx;

__device__ __forceinline__ ushortx f2bf(float x) {   // round-to-nearest-even bf16
    unsigned b = __float_as_uint(x);
    return (ushortx)((b + 0x7FFFu + ((b >> 16) & 1u)) >> 16);
}

// sum the 8 stat banks for entry e (e in 0..255)
__device__ __forceinline__ float stat_sum(const float* __restrict__ stat, int e) {
    float s = 0.f;
    #pragma unroll
    for (int k = 0; k < NSTK; ++k) s += stat[(k * 256 + e) * SPAD];
    return s;
}

// --- kNN: wave per 2 nodes, RADIX-SELECT top-20, LDS-staged positions -------
__device__ __forceinline__ void knn_radix(const float* __restrict__ pos,
                                          int* __restrict__ fwd, int bid,
                                          float* __restrict__ ps,   // >= 800 floats LDS
                                          int* __restrict__ ctr) {
    int wave = threadIdx.x >> 6, lane = threadIdx.x & 63;
    int g = bid / 25;                   // 25 blocks per graph (16 nodes each)
    const float* pg = pos + (size_t)g * NPG * 2;
    for (int idx = threadIdx.x; idx < NPG * 2; idx += 512) ps[idx] = pg[idx];
    __syncthreads();

    #pragma unroll 1
    for (int r2 = 0; r2 < 2; ++r2) {
        int i = bid * 16 + wave * 2 + r2;   // global node
        int li = i - g * NPG;               // graph-local index
        float xi = ps[li * 2], yi = ps[li * 2 + 1];

        unsigned kk[NSLOT], kx[NSLOT];      // key bits; key ^ selected-prefix
        #pragma unroll
        for (int s = 0; s < NSLOT; ++s) {
            int j = lane + (s << 6);
            unsigned kb = 0x7F800000u;      // +inf for invalid/self
            if (j < NPG && j != li) {
                float dx = __fsub_rn(xi, ps[j * 2]);
                float dy = __fsub_rn(yi, ps[j * 2 + 1]);
                float d2 = __fadd_rn(__fmul_rn(dx, dx), __fmul_rn(dy, dy));  // exact np rounding
                kb = __float_as_uint(d2);
            }
            kk[s] = kb; kx[s] = kb;
        }

        // MSB radix select: P = 20th-smallest key; R = #needed among ==P
        unsigned P = 0; int R = KNN;
        #pragma unroll
        for (int bit = 29; bit >= 0; --bit) {
            int c = 0;
            #pragma unroll
            for (int s = 0; s < NSLOT; ++s)
                c += __popcll(__ballot(kx[s] < (1u << bit)));   // prefix-match AND bit==0
            unsigned delta = (R > c) ? (1u << bit) : 0u;
            R -= (R > c) ? c : 0;
            P |= delta;
            #pragma unroll
            for (int s = 0; s < NSLOT; ++s) kx[s] ^= delta;
        }

        bool sel[NSLOT];
        int nsel = 0;
        #pragma unroll
        for (int s = 0; s < NSLOT; ++s) { sel[s] = kk[s] < P; nsel += sel[s] ? 1 : 0; }

        // threshold keys (kx==0 <=> kk==P): fast path when no tie competition
        int ceq = 0;
        #pragma unroll
        for (int s = 0; s < NSLOT; ++s) ceq += __popcll(__ballot(kx[s] == 0u));
        if (ceq == R) {
            #pragma unroll
            for (int s = 0; s < NSLOT; ++s)
                if (kx[s] == 0u) { sel[s] = true; nsel++; }
            R = 0;
        }
        #pragma unroll 1
        while (R > 0) {                 // rare: ties at threshold, take smallest j
            int bj = 0x7FFFFFFF;
            #pragma unroll
            for (int s = 0; s < NSLOT; ++s)
                if (kx[s] == 0 && !sel[s]) { int j = lane + (s << 6); bj = j < bj ? j : bj; }
            int m = bj;
            #pragma unroll
            for (int off = 32; off > 0; off >>= 1) { int o = __shfl_xor(m, off); m = o < m ? o : m; }
            if (bj == m && bj != 0x7FFFFFFF) {
                #pragma unroll
                for (int s = 0; s < NSLOT; ++s)
                    if ((lane + (s << 6)) == bj) { sel[s] = true; nsel++; }
            }
            R--;
        }

        // emit (order-free set); per-wave LDS counter (wave-lockstep safe)
        if (lane == 0) ctr[wave] = 0;
        int pos0 = atomicAdd(&ctr[wave], nsel);
        int w = 0;
        #pragma unroll
        for (int s = 0; s < NSLOT; ++s)
            if (sel[s]) { fwd[(size_t)i * KNN + pos0 + w] = lane + (s << 6); ++w; }
    }
}

// ---- mm tile (16 rows, 512 thr): [proj | BN+ELU+res] + hh(bf16) + scores ---
__device__ __forceinline__ void mm_tile(
        int tile, float* __restrict__ h, const float* __restrict__ gout,
        const float* __restrict__ stat, const float* __restrict__ gamma,
        const float* __restrict__ beta, const float* __restrict__ x,
        const float* __restrict__ pw, const float* __restrict__ pb,
        const float* __restrict__ w,
        const float* __restrict__ asrc, const float* __restrict__ adst,
        ushortx* __restrict__ hhb, float* __restrict__ ssrc, float* __restrict__ sdst,
        float (*hs)[EM]) {
    int t = threadIdx.x;               // 0..511
    int row0 = tile * 16;
    int cc0 = t & 127;
    float m = 0.f, rsd = 0.f, ga = 0.f, be = 0.f;
    if (gout) {                        // per-thread channel is fixed (t&127)
        m = stat_sum(stat, cc0) * (1.f / NN);
        float vr = stat_sum(stat, 128 + cc0) * (1.f / NN) - m * m;
        rsd = rsqrtf(vr + BNEPS);
        ga = gamma[cc0]; be = beta[cc0];
    }
    for (int idx = t; idx < 16 * EM; idx += 512) {
        int r = idx >> 7, c = idx & 127;   // c == cc0 (stride 512 preserves low7)
        size_t gi = (size_t)(row0 + r) * EM + c;
        float v;
        if (gout) {
            float bnv = (gout[gi] - m) * rsd * ga + be;
            bnv = bnv > 0.f ? bnv : __expf(bnv) - 1.f;   // elu (fast exp)
            v = bnv + h[gi];                        // residual
        } else {
            int n = row0 + r;                       // input projection
            v = x[n * 3 + 0] * pw[c] + x[n * 3 + 1] * pw[EM + c]
              + x[n * 3 + 2] * pw[2 * EM + c] + pb[c];
        }
        h[gi] = v;
        hs[r][c] = v;
    }
    __syncthreads();
    int cc = t & 127, q = t >> 7;      // q in 0..3 -> rows q*4+rr
    float acc[4] = {0, 0, 0, 0};
    const float* wp = w + cc;
    for (int k = 0; k < EM; k += 4) {
        float w0 = wp[(k + 0) * EM], w1 = wp[(k + 1) * EM];
        float w2 = wp[(k + 2) * EM], w3 = wp[(k + 3) * EM];
        #pragma unroll
        for (int rr = 0; rr < 4; ++rr) {
            const float4 hv = *(const float4*)&hs[q * 4 + rr][k];
            acc[rr] = fmaf(hv.x, w0, fmaf(hv.y, w1, fmaf(hv.z, w2, fmaf(hv.w, w3, acc[rr]))));
        }
    }
    #pragma unroll
    for (int rr = 0; rr < 4; ++rr)
        hhb[(size_t)(row0 + q * 4 + rr) * EM + cc] = f2bf(acc[rr]);   // bf16 for PV
    __syncthreads();
    #pragma unroll
    for (int rr = 0; rr < 4; ++rr) hs[q * 4 + rr][cc] = acc[rr];      // fp32 for scores
    __syncthreads();
    if (t < 16 * NH) {
        int row = t >> 3, hd = t & 7;
        const float* ap = asrc + hd * HD;
        const float* dp = adst + hd * HD;
        float s1 = 0.f, s2 = 0.f;
        #pragma unroll
        for (int d = 0; d < HD; ++d) {
            float v = hs[row][hd * HD + d];
            s1 += v * ap[d]; s2 += v * dp[d];
        }
        ssrc[(size_t)(row0 + row) * NH + hd] = s1;
        sdst[(size_t)(row0 + row) * NH + hd] = s2;
    }
}

// ---- kernel 1: kNN (blocks 0..399)  ||  layer-0 mm (blocks 400..799) -------
__global__ __launch_bounds__(512) void k1_kernel(
        const float* __restrict__ pos, int* __restrict__ fwd,
        float* __restrict__ h, const float* __restrict__ x,
        const float* __restrict__ pw, const float* __restrict__ pb,
        const float* __restrict__ w0,
        const float* __restrict__ asrc0, const float* __restrict__ adst0,
        ushortx* __restrict__ hhb, float* __restrict__ ssrc, float* __restrict__ sdst,
        float* __restrict__ statz, float* __restrict__ out) {
    __shared__ float hs[16][EM];
    __shared__ int ctr[8];
    int bid = blockIdx.x;
    if (bid < KNB) {
        knn_radix(pos, fwd, bid, (float*)hs, ctr);
    } else {
        int tile = bid - KNB;
        if (tile == 0) {
            #pragma unroll
            for (int k = 0; k < NSTK * 256 / 512; ++k)
                statz[(k * 512 + threadIdx.x) * SPAD] = 0.f;
        } else if (tile == 1) {
            for (int idx = threadIdx.x; idx < BG * EM; idx += 512)
                out[(size_t)NN * EM + idx] = 0.f;   // zero graph-mean tail
        }
        mm_tile(tile, h, nullptr, nullptr, nullptr, nullptr,
                x, pw, pb, w0, asrc0, adst0, hhb, ssrc, sdst, hs);
    }
}

// ---- mm kernel for layers 1,2 (zeroes next stat accumulator) ---------------
__global__ __launch_bounds__(512) void mm_kernel(
        float* __restrict__ h, const float* __restrict__ gout,
        const float* __restrict__ stat, const float* __restrict__ gamma,
        const float* __restrict__ beta, const float* __restrict__ w,
        const float* __restrict__ asrc, const float* __restrict__ adst,
        ushortx* __restrict__ hhb, float* __restrict__ ssrc, float* __restrict__ sdst,
        float* __restrict__ statz) {
    __shared__ float hs[16][EM];
    if (blockIdx.x == 0) {
        #pragma unroll
        for (int k = 0; k < NSTK * 256 / 512; ++k)
            statz[(k * 512 + threadIdx.x) * SPAD] = 0.f;
    }
    mm_tile(blockIdx.x, h, gout, stat, gamma, beta,
            nullptr, nullptr, nullptr, w, asrc, adst, hhb, ssrc, sdst, hs);
}

// ---- attention: 16 nodes/block, register softmax; FIRST builds adjacency ---
template<int FIRST>
__global__ __launch_bounds__(512) void attn_kernel(const ushortx* __restrict__ hhb,
                                                   const int* __restrict__ fwd,
                                                   const float* __restrict__ ssrc,
                                                   const float* __restrict__ sdst,
                                                   const float* __restrict__ bias,
                                                   float* __restrict__ gout,
                                                   float* __restrict__ statl,
                                                   int* __restrict__ nbrg,
                                                   int* __restrict__ cntg) {
    __shared__ float sc[8 * 1024];            // per-wave exp-score slab [jj*8+hd]
    __shared__ int   nb[16][MAXDEG];          // graph-LOCAL neighbor ids (8 KB)
    __shared__ int cnt16[16];
    __shared__ float red[256];
    __shared__ float ssl[NPG * NH];           // graph's ssrc table (12.5 KB)
    int t = threadIdx.x, wv = t >> 6, lane = t & 63;
    int bid = blockIdx.x;
    int g = bid / 25;                          // 25 blocks per graph (400/16)
    int r0g = (bid - g * 25) * 16;             // graph-local row base
    int sbase = g * NPG;

    if (t < 256) red[t] = 0.f;
    // stage ssrc for the whole graph (coalesced float4)
    for (int idx = t; idx < NPG * NH / 4; idx += 512)
        ((float4*)ssl)[idx] = ((const float4*)(ssrc + (size_t)sbase * NH))[idx];
    int cA, cB;

    if (FIRST) {
        __shared__ unsigned bm[16][16];       // 16 rows x 512-bit adjacency
        __shared__ unsigned short roff[16][13];
        if (t < 256) ((unsigned*)bm)[t] = 0u;
        __syncthreads();
        const int* fg = fwd + (size_t)sbase * KNN;
        for (int e = t; e < NPG * KNN; e += 512) {
            int src = e / KNN;                 // graph-local
            int dst = fg[e];                   // graph-local
            int rs = src - r0g, rd = dst - r0g;
            if ((unsigned)rs < 16u) atomicOr(&bm[rs][dst >> 5], 1u << (dst & 31));
            if ((unsigned)rd < 16u) atomicOr(&bm[rd][src >> 5], 1u << (src & 31));
        }
        if (t < 16) atomicOr(&bm[t][(r0g + t) >> 5], 1u << ((r0g + t) & 31));  // self
        __syncthreads();
        if (t < 16) {                          // prefix popcounts per row
            int off = 0;
            #pragma unroll
            for (int w = 0; w < 13; ++w) { roff[t][w] = (unsigned short)off; off += __popc(bm[t][w]); }
            cnt16[t] = off < MAXDEG ? off : MAXDEG;
            cntg[bid * 16 + t] = cnt16[t];
        }
        __syncthreads();
        if (t < 16 * 13) {                     // (row,word) emit tasks
            int row = t / 13, w = t - row * 13;
            unsigned m = bm[row][w];
            int c = roff[row][w];
            int jb = w * 32;
            while (m) {
                int b = __ffs(m) - 1;
                m &= m - 1;
                if (c < MAXDEG) nb[row][c++] = jb + b;
            }
        }
        __syncthreads();
        // persist for layers 1,2 (coalesced; wave wv owns rows 2wv, 2wv+1)
        #pragma unroll
        for (int r2 = 0; r2 < 2; ++r2) {
            int row = wv * 2 + r2;
            int c = cnt16[row];
            int* dst = nbrg + ((size_t)bid * 16 + row) * MAXDEG;
            for (int j = lane; j < c; j += 64) dst[j] = nb[row][j];
        }
        cA = cnt16[wv * 2];
        cB = cnt16[wv * 2 + 1];
    } else {
        // per-wave: each wave only touches its own 2 rows -> single block sync
        cA = cntg[bid * 16 + wv * 2];          // broadcast scalar loads
        cB = cntg[bid * 16 + wv * 2 + 1];
        const int* srcA = nbrg + ((size_t)bid * 16 + wv * 2) * MAXDEG;
        const int* srcB = srcA + MAXDEG;
        for (int j = lane; j < cA; j += 64) nb[wv * 2][j] = srcA[j];
        for (int j = lane; j < cB; j += 64) nb[wv * 2 + 1][j] = srcB[j];
        __syncthreads();                       // orders red zero + ssl staging
    }

    float* scw = sc + wv * 1024;
    int hd = lane & 7, sub = lane >> 3, h0 = lane >> 3;
    float s1a = 0.f, s2a = 0.f, s1b = 0.f, s2b = 0.f;
    int iA = bid * 16 + wv * 2;
    float sdA = sdst[iA * NH + hd];            // hoisted independent loads
    float sdB = sdst[(iA + 1) * NH + hd];
    float2 bv = *(const float2*)(bias + 2 * lane);

    #pragma unroll 1
    for (int r2 = 0; r2 < 2; ++r2) {
        int nlo = wv * 2 + r2;                 // block-local node
        int i = iA + r2;                       // global node
        int c = r2 ? cB : cA;
        float sd = r2 ? sdB : sdA;
        int cp = (c + 7) & ~7;                 // pad to x8 for PV unroll
        if (lane < cp - c) nb[nlo][c + lane] = r0g + nlo;   // valid (self) pad ids

        // register-resident scores: lane owns jj = sub + 8k (same map as reduce)
        int nk = cp >> 3;                      // <= 16 slots
        float rv[16];
        float mx = -INFINITY;
        #pragma unroll
        for (int k = 0; k < 16; ++k) {
            if (k < nk) {
                int jj = sub + 8 * k;
                float v = -INFINITY;
                if (jj < c) {
                    v = sd + ssl[nb[nlo][jj] * NH + hd];    // LDS gather
                    v = v >= 0.f ? v : NEGS * v;            // leaky_relu
                    mx = fmaxf(mx, v);
                }
                rv[k] = v;
            }
        }
        #pragma unroll
        for (int off = 8; off < 64; off <<= 1) mx = fmaxf(mx, __shfl_xor(mx, off));
        float s = 0.f;
        #pragma unroll
        for (int k = 0; k < 16; ++k) {
            if (k < nk) {
                int jj = sub + 8 * k;
                float e = 0.f;
                if (jj < c) { e = __expf(rv[k] - mx); s += e; }
                scw[jj * 8 + hd] = e;          // single LDS write (pads = 0)
            }
        }
        #pragma unroll
        for (int off = 8; off < 64; off <<= 1) s += __shfl_xor(s, off);
        float inv = 1.f / s;                   // lane k (k<8) holds inv for head k
        asm volatile("s_waitcnt lgkmcnt(0)" ::: "memory");

        // PV: lane owns channels (2*lane, 2*lane+1); 8 outstanding gathers
        float invh = __shfl(inv, h0);
        const unsigned* hp32 = (const unsigned*)hhb;
        float acc0 = 0.f, acc1 = 0.f;
        for (int jj = 0; jj < cp; jj += 8) {
            float a0 = scw[(jj + 0) * 8 + h0];
            float a1 = scw[(jj + 1) * 8 + h0];
            float a2 = scw[(jj + 2) * 8 + h0];
            float a3 = scw[(jj + 3) * 8 + h0];
            float a4 = scw[(jj + 4) * 8 + h0];
            float a5 = scw[(jj + 5) * 8 + h0];
            float a6 = scw[(jj + 6) * 8 + h0];
            float a7 = scw[(jj + 7) * 8 + h0];
            unsigned u0 = hp32[(size_t)(sbase + nb[nlo][jj + 0]) * 64 + lane];
            unsigned u1 = hp32[(size_t)(sbase + nb[nlo][jj + 1]) * 64 + lane];
            unsigned u2 = hp32[(size_t)(sbase + nb[nlo][jj + 2]) * 64 + lane];
            unsigned u3 = hp32[(size_t)(sbase + nb[nlo][jj + 3]) * 64 + lane];
            unsigned u4 = hp32[(size_t)(sbase + nb[nlo][jj + 4]) * 64 + lane];
            unsigned u5 = hp32[(size_t)(sbase + nb[nlo][jj + 5]) * 64 + lane];
            unsigned u6 = hp32[(size_t)(sbase + nb[nlo][jj + 6]) * 64 + lane];
            unsigned u7 = hp32[(size_t)(sbase + nb[nlo][jj + 7]) * 64 + lane];
            acc0 += a0 * __uint_as_float(u0 << 16) + a1 * __uint_as_float(u1 << 16)
                  + a2 * __uint_as_float(u2 << 16) + a3 * __uint_as_float(u3 << 16);
            acc1 += a0 * __uint_as_float(u0 & 0xFFFF0000u) + a1 * __uint_as_float(u1 & 0xFFFF0000u)
                  + a2 * __uint_as_float(u2 & 0xFFFF0000u) + a3 * __uint_as_float(u3 & 0xFFFF0000u);
            acc0 += a4 * __uint_as_float(u4 << 16) + a5 * __uint_as_float(u5 << 16)
                  + a6 * __uint_as_float(u6 << 16) + a7 * __uint_as_float(u7 << 16);
            acc1 += a4 * __uint_as_float(u4 & 0xFFFF0000u) + a5 * __uint_as_float(u5 & 0xFFFF0000u)
                  + a6 * __uint_as_float(u6 & 0xFFFF0000u) + a7 * __uint_as_float(u7 & 0xFFFF0000u);
        }
        float v0 = acc0 * invh + bv.x;
        float v1 = acc1 * invh + bv.y;
        float2 ov; ov.x = v0; ov.y = v1;
        *(float2*)(gout + (size_t)i * EM + 2 * lane) = ov;
        s1a += v0; s2a += v0 * v0;
        s1b += v1; s2b += v1 * v1;
    }

    // BN stat partials -> bank bid&7 (8-way contention split)
    atomicAdd(&red[2 * lane], s1a);
    atomicAdd(&red[2 * lane + 1], s1b);
    atomicAdd(&red[128 + 2 * lane], s2a);
    atomicAdd(&red[128 + 2 * lane + 1], s2b);
    __syncthreads();
    if (t < 256)
        atomicAdd(&statl[((bid & (NSTK - 1)) * 256 + t) * SPAD], red[t]);
}

// ---- final: BN+ELU+residual (layer 2) -> node out + graph-mean atomics -----
__global__ __launch_bounds__(512) void finish_kernel(const float* __restrict__ gout,
                                                     const float* __restrict__ stat,
                                                     const float* __restrict__ gamma,
                                                     const float* __restrict__ beta,
                                                     const float* __restrict__ h,
                                                     float* __restrict__ out) {
    int bid = blockIdx.x;        // 400 blocks x 16 rows (25 blocks per graph)
    int g = bid / 25;
    int row0 = bid * 16;
    int t = threadIdx.x, c = t & 127;
    float m  = stat_sum(stat, c) * (1.f / NN);
    float vr = stat_sum(stat, 128 + c) * (1.f / NN) - m * m;
    float rs = rsqrtf(vr + BNEPS);
    float ga = gamma[c], be = beta[c];
    float s = 0.f;
    #pragma unroll
    for (int k = 0; k < 4; ++k) {
        int idx = k * 512 + t;               // c stays t&127; row = k*4 + (t>>7)
        int r = idx >> 7;
        size_t gi = (size_t)(row0 + r) * EM + c;
        float v = (gout[gi] - m) * rs * ga + be;
        v = v > 0.f ? v : __expf(v) - 1.f;
        v += h[gi];
        out[gi] = v;
        s += v;
    }
    __shared__ float l1[512];
    l1[t] = s;
    __syncthreads();
    if (t < 128)
        atomicAdd(&out[(size_t)NN * EM + g * EM + t],
                  (l1[t] + l1[t + 128] + l1[t + 256] + l1[t + 384]) * (1.f / NPG));
}

extern "C" void kernel_launch(void* const* d_in, const int* in_sizes, int n_in,
                              void* d_out, int out_size, void* d_ws, size_t ws_size,
                              hipStream_t stream) {
    const float* x      = (const float*)d_in[0];
    const float* pos    = (const float*)d_in[1];
    // d_in[2] = batch (int32), unused: graphs are contiguous blocks of 400
    const float* proj_w = (const float*)d_in[3];
    const float* proj_b = (const float*)d_in[4];
    const float* lin_w  = (const float*)d_in[5];
    const float* asrc   = (const float*)d_in[6];
    const float* adst   = (const float*)d_in[7];
    const float* gbias  = (const float*)d_in[8];
    const float* gamma  = (const float*)d_in[9];
    const float* beta   = (const float*)d_in[10];
    float* out = (float*)d_out;

    char* p = (char*)d_ws;
    auto take = [&](size_t bytes) { char* q = p; p += (bytes + 63) & ~(size_t)63; return q; };
    int*     fwd  = (int*)take((size_t)NN * KNN * 4);
    int*     nbrg = (int*)take((size_t)NN * MAXDEG * 4);
    int*     cntg = (int*)take((size_t)NN * 4);
    float*   h    = (float*)take((size_t)NN * EM * 4);
    ushortx* hhb  = (ushortx*)take((size_t)NN * EM * 2);
    float*   gout = (float*)take((size_t)NN * EM * 4);
    float*   ssrc = (float*)take((size_t)NN * NH * 4);
    float*   sdst = (float*)take((size_t)NN * NH * 4);
    float*   statA = (float*)take((size_t)STSZ * 4);
    float*   statB = (float*)take((size_t)STSZ * 4);
    float*   statv[2] = {statA, statB};

    // 1: kNN (radix, 2 nodes/wave, LDS pos) || layer-0 mm (+zero stat, tail)
    k1_kernel<<<KNB + MMB, 512, 0, stream>>>(pos, fwd, h, x, proj_w, proj_b,
                                             lin_w, asrc, adst, hhb, ssrc, sdst,
                                             statv[0], out);
    // 2: attn layer 0 (builds + persists adjacency) -> statv[0] banks
    attn_kernel<1><<<ANB, 512, 0, stream>>>(hhb, fwd, ssrc, sdst, gbias, gout,
                                            statv[0], nbrg, cntg);
    // 3: mm layer 1 (reads statv[0], zeroes statv[1])
    mm_kernel<<<MMB, 512, 0, stream>>>(h, gout, statv[0], gamma, beta,
                                       lin_w + (size_t)EM * EM, asrc + EM, adst + EM,
                                       hhb, ssrc, sdst, statv[1]);
    // 4: attn layer 1 (loads adjacency per-wave) -> statv[1] banks
    attn_kernel<0><<<ANB, 512, 0, stream>>>(hhb, fwd, ssrc, sdst, gbias + EM, gout,
                                            statv[1], nbrg, cntg);
    // 5: mm layer 2 (reads statv[1], zeroes statv[0])
    mm_kernel<<<MMB, 512, 0, stream>>>(h, gout, statv[1], gamma + EM, beta + EM,
                                       lin_w + (size_t)2 * EM * EM, asrc + 2 * EM, adst + 2 * EM,
                                       hhb, ssrc, sdst, statv[0]);
    // 6: attn layer 2 (loads adjacency per-wave) -> statv[0] banks
    attn_kernel<0><<<ANB, 512, 0, stream>>>(hhb, fwd, ssrc, sdst, gbias + 2 * EM, gout,
                                            statv[0], nbrg, cntg);
    // 7: finish (400 blocks, matches mm tiling)
    finish_kernel<<<MMB, 512, 0, stream>>>(gout, statv[0],
                                           gamma + 2 * EM, beta + 2 * EM, h, out);
}